// Round 3
// baseline (886.086 us; speedup 1.0000x reference)
//
#include <hip/hip_runtime.h>
#include <hip/hip_bf16.h>

typedef __bf16 bf16x8 __attribute__((ext_vector_type(8)));
typedef float floatx4 __attribute__((ext_vector_type(4)));

#define NEG_BIG (-1e30f)

static __device__ __forceinline__ float exp_safe(float a) {
    return expf(fmaxf(a, -60.0f));   // exp(-60) ~ 8.8e-27 == numerically 0
}

// load 8 consecutive elements as bf16[8]
static __device__ __forceinline__ void load8(const float* p, __bf16* e) {
    float4 f0 = *(const float4*)p;
    float4 f1 = *(const float4*)(p + 4);
    e[0] = (__bf16)f0.x; e[1] = (__bf16)f0.y; e[2] = (__bf16)f0.z; e[3] = (__bf16)f0.w;
    e[4] = (__bf16)f1.x; e[5] = (__bf16)f1.y; e[6] = (__bf16)f1.z; e[7] = (__bf16)f1.w;
}
static __device__ __forceinline__ void load8(const __bf16* p, __bf16* e) {
    union { uint4 u; __bf16 b[8]; } t;
    t.u = *(const uint4*)p;
    #pragma unroll
    for (int i = 0; i < 8; ++i) e[i] = t.b[i];
}

// ---------------------------------------------------------------------------
// Generic GEMM: C[M,N] = A[M,K] @ B[K,N], row-major; bf16 MFMA, fp32 accum.
// A/B converted to bf16 at staging. Block = 256 threads (4 waves), tile 64x64.
// ---------------------------------------------------------------------------
template <typename TA, typename TB, typename TC>
__global__ __launch_bounds__(256) void gemm_any(
    const TA* __restrict__ A,
    const TB* __restrict__ B,
    TC* __restrict__ C,
    int M, int N, int K)
{
    __shared__ __bf16 As[64 * 32];   // [row][k]
    __shared__ __bf16 Bs[64 * 32];   // transposed: [n][k]

    const int tid  = threadIdx.x;
    const int wave = tid >> 6;
    const int lane = tid & 63;
    const int quad = lane >> 4;
    const int l15  = lane & 15;

    const int bm = blockIdx.y * 64;
    const int bn = blockIdx.x * 64;

    floatx4 acc[4];
    #pragma unroll
    for (int i = 0; i < 4; ++i) acc[i] = floatx4{0.f, 0.f, 0.f, 0.f};

    const int a_row = tid >> 2;        // 0..63
    const int a_cg  = (tid & 3) * 8;   // 0,8,16,24
    const int b_kr  = tid >> 3;        // 0..31
    const int b_cg  = (tid & 7) * 8;   // 0..56

    for (int k0 = 0; k0 < K; k0 += 32) {
        __bf16 ae[8], be[8];
        load8(A + (size_t)(bm + a_row) * K + k0 + a_cg, ae);
        load8(B + (size_t)(k0 + b_kr) * N + bn + b_cg, be);
        __syncthreads();  // previous iteration's LDS reads complete
        union { uint4 u; __bf16 b[8]; } pk;
        #pragma unroll
        for (int i = 0; i < 8; ++i) pk.b[i] = ae[i];
        *(uint4*)(&As[a_row * 32 + a_cg]) = pk.u;
        #pragma unroll
        for (int e = 0; e < 8; ++e) Bs[(b_cg + e) * 32 + b_kr] = be[e];
        __syncthreads();

        bf16x8 af = *(const bf16x8*)(&As[(wave * 16 + l15) * 32 + quad * 8]);
        #pragma unroll
        for (int nb = 0; nb < 4; ++nb) {
            bf16x8 bf = *(const bf16x8*)(&Bs[(nb * 16 + l15) * 32 + quad * 8]);
            acc[nb] = __builtin_amdgcn_mfma_f32_16x16x32_bf16(af, bf, acc[nb], 0, 0, 0);
        }
    }

    #pragma unroll
    for (int nb = 0; nb < 4; ++nb) {
        #pragma unroll
        for (int r = 0; r < 4; ++r) {
            int row = bm + wave * 16 + quad * 4 + r;
            int col = bn + nb * 16 + l15;
            C[(size_t)row * N + col] = (TC)acc[nb][r];
        }
    }
}

// ---------------------------------------------------------------------------
// RoPE in-place on bf16 buf [B*N, nheads, 128]; rotate pairs (j, j+64),
// angle = n * theta^(-j/64), n = row % 1024.
// ---------------------------------------------------------------------------
__global__ void rope_kernel(__bf16* __restrict__ buf, int nheads, int total)
{
    int idx = blockIdx.x * blockDim.x + threadIdx.x;
    if (idx >= total) return;
    int j    = idx & 63;
    int rest = idx >> 6;
    int hh   = rest % nheads;
    int row  = rest / nheads;
    int n    = row & 1023;

    float inv_freq = powf(10000.0f, -(float)j / 64.0f);
    float ang = (float)n * inv_freq;
    float c = cosf(ang), s = sinf(ang);

    size_t base = ((size_t)row * nheads + hh) * 128;
    float x1 = (float)buf[base + j];
    float x2 = (float)buf[base + 64 + j];
    buf[base + j]      = (__bf16)(x1 * c - x2 * s);
    buf[base + 64 + j] = (__bf16)(x1 * s + x2 * c);
}

// ---------------------------------------------------------------------------
// Causal flash attention. Grid: (N/64, B*H*I). Block 256 = 4 waves.
// Q  : [B, N, H, I, 128] bf16 (post-RoPE)
// Kt : [B, N, H, 128]    bf16 (post-RoPE)
// V  : [B, N, H, 128]    bf16
// O  : [B, N, H, I, 128] bf16 -- MAY ALIAS Q (no __restrict__; each wave
//      preloads its Q rows before any O write; slots disjoint across blocks)
// ---------------------------------------------------------------------------
__global__ __launch_bounds__(256) void attn_kernel(
    const __bf16* Q,
    const __bf16* __restrict__ Kt,
    const __bf16* __restrict__ V,
    __bf16* O)
{
    const int NSEQ = 1024, H = 8, I = 4, D = 128;
    __shared__ __bf16 Ks[32 * 128];      // [key][dim]
    __shared__ __bf16 Vs[128 * 32];      // [vdim][key]
    __shared__ __bf16 Ps[4][16 * 32];    // per-wave P [qrow][key]

    const int tid  = threadIdx.x;
    const int wave = tid >> 6;
    const int lane = tid & 63;
    const int quad = lane >> 4;
    const int l15  = lane & 15;

    const int qb  = blockIdx.x * 64;
    const int bhi = blockIdx.y;          // b*32 + h*4 + i
    const int b = bhi >> 5, h = (bhi >> 2) & 7, i = bhi & 3;

    // preload this wave's Q fragments (16 queries x 128 dims)
    const int qrow = qb + wave * 16 + l15;
    const __bf16* qbase = Q + ((size_t)(b * NSEQ + qrow) * (H * I) + (h * I + i)) * D;
    bf16x8 qf[4];
    #pragma unroll
    for (int c = 0; c < 4; ++c)
        qf[c] = *(const bf16x8*)(qbase + c * 32 + quad * 8);

    floatx4 o_acc[8];
    #pragma unroll
    for (int t = 0; t < 8; ++t) o_acc[t] = floatx4{0.f, 0.f, 0.f, 0.f};
    float m_run[4], l_run[4];
    #pragma unroll
    for (int r = 0; r < 4; ++r) { m_run[r] = NEG_BIG; l_run[r] = 0.f; }

    const float scale = 0.08838834764831845f;   // 1/sqrt(128)

    const int kt_end = qb + 64;
    for (int kt = 0; kt < kt_end; kt += 32) {
        __syncthreads();   // all waves done reading previous K/V tiles
        // stage K tile [32][128] row-major, V tile transposed [128][32]
        #pragma unroll
        for (int it = 0; it < 2; ++it) {
            int cch = tid + it * 256;            // 0..511
            int key = cch >> 4;
            int cg  = (cch & 15) * 8;
            size_t grow = ((size_t)(b * NSEQ + kt + key) * H + h) * D + cg;
            union { uint4 u; __bf16 e[8]; } kv, vv;
            kv.u = *(const uint4*)(Kt + grow);
            vv.u = *(const uint4*)(V + grow);
            *(uint4*)(&Ks[key * 128 + cg]) = kv.u;
            #pragma unroll
            for (int e = 0; e < 8; ++e) Vs[(cg + e) * 32 + key] = vv.e[e];
        }
        __syncthreads();

        // S = Q K^T for two 16-key subtiles
        floatx4 s0 = floatx4{0.f, 0.f, 0.f, 0.f};
        floatx4 s1 = floatx4{0.f, 0.f, 0.f, 0.f};
        #pragma unroll
        for (int c = 0; c < 4; ++c) {
            bf16x8 k0 = *(const bf16x8*)(&Ks[(l15) * 128 + c * 32 + quad * 8]);
            bf16x8 k1 = *(const bf16x8*)(&Ks[(16 + l15) * 128 + c * 32 + quad * 8]);
            s0 = __builtin_amdgcn_mfma_f32_16x16x32_bf16(qf[c], k0, s0, 0, 0, 0);
            s1 = __builtin_amdgcn_mfma_f32_16x16x32_bf16(qf[c], k1, s1, 0, 0, 0);
        }

        // scale + causal mask + online softmax (finite math only)
        const int qi  = qb + wave * 16 + quad * 4;   // + r
        const int kj0 = kt + l15;
        const int kj1 = kt + 16 + l15;
        float alpha[4];
        #pragma unroll
        for (int r = 0; r < 4; ++r) {
            float v0 = (kj0 <= qi + r) ? s0[r] * scale : NEG_BIG;
            float v1 = (kj1 <= qi + r) ? s1[r] * scale : NEG_BIG;
            s0[r] = v0; s1[r] = v1;
            float m = fmaxf(v0, v1);
            #pragma unroll
            for (int off = 1; off < 16; off <<= 1)
                m = fmaxf(m, __shfl_xor(m, off, 64));
            float mnew = fmaxf(m_run[r], m);
            alpha[r]  = exp_safe(m_run[r] - mnew);
            m_run[r]  = mnew;
        }
        #pragma unroll
        for (int r = 0; r < 4; ++r) {
            float p0 = exp_safe(s0[r] - m_run[r]);
            float p1 = exp_safe(s1[r] - m_run[r]);
            float srow = p0 + p1;
            #pragma unroll
            for (int off = 1; off < 16; off <<= 1)
                srow += __shfl_xor(srow, off, 64);
            l_run[r] = l_run[r] * alpha[r] + srow;
            Ps[wave][(quad * 4 + r) * 32 + l15]      = (__bf16)p0;
            Ps[wave][(quad * 4 + r) * 32 + 16 + l15] = (__bf16)p1;
            #pragma unroll
            for (int t = 0; t < 8; ++t) o_acc[t][r] *= alpha[r];
        }
        __syncthreads();

        // O += P @ V
        bf16x8 pa = *(const bf16x8*)(&Ps[wave][l15 * 32 + quad * 8]);
        #pragma unroll
        for (int t = 0; t < 8; ++t) {
            bf16x8 vf = *(const bf16x8*)(&Vs[(t * 16 + l15) * 32 + quad * 8]);
            o_acc[t] = __builtin_amdgcn_mfma_f32_16x16x32_bf16(pa, vf, o_acc[t], 0, 0, 0);
        }
    }

    // normalize + store
    #pragma unroll
    for (int r = 0; r < 4; ++r) {
        float inv = 1.0f / l_run[r];
        int q = qb + wave * 16 + quad * 4 + r;
        __bf16* ob = O + ((size_t)(b * NSEQ + q) * (H * I) + (h * I + i)) * D;
        #pragma unroll
        for (int t = 0; t < 8; ++t)
            ob[t * 16 + l15] = (__bf16)(o_acc[t][r] * inv);
    }
}

// ---------------------------------------------------------------------------
extern "C" void kernel_launch(void* const* d_in, const int* in_sizes, int n_in,
                              void* d_out, int out_size, void* d_ws, size_t ws_size,
                              hipStream_t stream)
{
    // Reference dtypes are float32 (jnp.float32 throughout setup_inputs).
    const float* x  = (const float*)d_in[0];   // [2,1024,2048]
    const float* Wq = (const float*)d_in[1];   // [2048, 8,4,128] = [2048,4096]
    const float* Wk = (const float*)d_in[2];   // [2048, 8,128]   = [2048,1024]
    const float* Wv = (const float*)d_in[3];   // [2048, 8,128]   = [2048,1024]
    const float* Wo = (const float*)d_in[4];   // [8,4,128, 2048] = [4096,2048]
    float* out = (float*)d_out;                // [2,1024,2048] fp32

    char* ws = (char*)d_ws;                    // need 24 MB
    __bf16* q  = (__bf16*)(ws);                                // 16 MB (q, then attn out in-place)
    __bf16* k  = (__bf16*)(ws + (size_t)16 * 1024 * 1024);     //  4 MB
    __bf16* v  = (__bf16*)(ws + (size_t)20 * 1024 * 1024);     //  4 MB
    __bf16* ao = q;                                            // alias (safe, see attn_kernel)

    const int M = 2 * 1024;   // B*N
    dim3 blk(256);

    // projections (fp32 in, bf16 out)
    gemm_any<float, float, __bf16><<<dim3(4096 / 64, M / 64), blk, 0, stream>>>(x, Wq, q, M, 4096, 2048);
    gemm_any<float, float, __bf16><<<dim3(1024 / 64, M / 64), blk, 0, stream>>>(x, Wk, k, M, 1024, 2048);
    gemm_any<float, float, __bf16><<<dim3(1024 / 64, M / 64), blk, 0, stream>>>(x, Wv, v, M, 1024, 2048);

    // RoPE (q: 32 heads, k: 8 heads)
    int totq = M * 32 * 64;
    int totk = M * 8 * 64;
    rope_kernel<<<(totq + 255) / 256, blk, 0, stream>>>(q, 32, totq);
    rope_kernel<<<(totk + 255) / 256, blk, 0, stream>>>(k, 8, totk);

    // attention: grid (qtiles, B*H*I)
    attn_kernel<<<dim3(1024 / 64, 2 * 8 * 4), blk, 0, stream>>>(q, k, v, ao);

    // output projection (bf16 x fp32 -> fp32)
    gemm_any<__bf16, float, float><<<dim3(2048 / 64, M / 64), blk, 0, stream>>>(ao, Wo, out, M, 2048, 4096);
}

// Round 4
// 444.005 us; speedup vs baseline: 1.9957x; 1.9957x over previous
//
#include <hip/hip_runtime.h>
#include <hip/hip_bf16.h>

typedef __bf16 bf16x8 __attribute__((ext_vector_type(8)));
typedef float floatx4 __attribute__((ext_vector_type(4)));

#define NEG_BIG (-1e30f)

static __device__ __forceinline__ float exp_safe(float a) {
    return expf(fmaxf(a, -60.0f));   // exp(-60) ~ 8.8e-27 == numerically 0
}

// async global->LDS, 16B per lane; LDS dst = wave-uniform base + lane*16
static __device__ __forceinline__ void async_cp16(const __bf16* g, __bf16* l) {
    typedef const __attribute__((address_space(1))) unsigned int gu32;
    typedef __attribute__((address_space(3))) unsigned int lu32;
    __builtin_amdgcn_global_load_lds((gu32*)g, (lu32*)l, 16, 0, 0);
}

// ---------------------------------------------------------------------------
// fp32 -> bf16 elementwise convert (n multiple of 8)
// ---------------------------------------------------------------------------
__global__ void convert_kernel(const float* __restrict__ src,
                               __bf16* __restrict__ dst, int n8)
{
    int idx = blockIdx.x * blockDim.x + threadIdx.x;
    if (idx >= n8) return;
    const float* p = src + (size_t)idx * 8;
    float4 f0 = *(const float4*)p;
    float4 f1 = *(const float4*)(p + 4);
    union { uint4 u; __bf16 b[8]; } o;
    o.b[0] = (__bf16)f0.x; o.b[1] = (__bf16)f0.y; o.b[2] = (__bf16)f0.z; o.b[3] = (__bf16)f0.w;
    o.b[4] = (__bf16)f1.x; o.b[5] = (__bf16)f1.y; o.b[6] = (__bf16)f1.z; o.b[7] = (__bf16)f1.w;
    *(uint4*)(dst + (size_t)idx * 8) = o.u;
}

// ---------------------------------------------------------------------------
// fp32 [R][C] -> bf16 [C][R] transpose-convert. Block (32,8), tile 32x32.
// ---------------------------------------------------------------------------
__global__ void transpose_cvt_kernel(const float* __restrict__ src,
                                     __bf16* __restrict__ dst, int R, int C)
{
    __shared__ float tile[32][33];
    const int tx = threadIdx.x, ty = threadIdx.y;
    const int c0 = blockIdx.x * 32, r0 = blockIdx.y * 32;
    #pragma unroll
    for (int j = 0; j < 4; ++j)
        tile[ty * 4 + j][tx] = src[(size_t)(r0 + ty * 4 + j) * C + c0 + tx];
    __syncthreads();
    #pragma unroll
    for (int j = 0; j < 4; ++j)
        dst[(size_t)(c0 + ty * 4 + j) * R + r0 + tx] = (__bf16)tile[tx][ty * 4 + j];
}

// ---------------------------------------------------------------------------
// bf16 transpose of the V columns of qkv into vt[b*8+h][128][1024].
// qkv: [2048][6144], V at cols 5120 + h*128 + vd. Block (32,8), grid (32,4,16).
// ---------------------------------------------------------------------------
__global__ void vtrans_kernel(const __bf16* __restrict__ qkv,
                              __bf16* __restrict__ vt)
{
    __shared__ __bf16 tile[32][33];
    const int tx = threadIdx.x, ty = threadIdx.y;
    const int k0 = blockIdx.x * 32, v0 = blockIdx.y * 32;
    const int bh = blockIdx.z;
    const int b = bh >> 3, h = bh & 7;
    #pragma unroll
    for (int j = 0; j < 4; ++j)
        tile[ty * 4 + j][tx] =
            qkv[(size_t)(b * 1024 + k0 + ty * 4 + j) * 6144 + 5120 + h * 128 + v0 + tx];
    __syncthreads();
    #pragma unroll
    for (int j = 0; j < 4; ++j)
        vt[((size_t)bh * 128 + v0 + ty * 4 + j) * 1024 + k0 + tx] = tile[tx][ty * 4 + j];
}

// ---------------------------------------------------------------------------
// GEMM (m97 structure): C[M][N] = A[M][K] * Bt[N][K]^T, A/Bt bf16 row-major.
// Block 256 = 4 waves, tile 128x128, BK=32, global_load_lds width-16 staging.
// Wave w (wr=w>>1, wc=w&1) computes the 64x64 subtile (wr*64, wc*64).
// ---------------------------------------------------------------------------
template <typename TC>
__global__ __launch_bounds__(256) void gemm_bt(
    const __bf16* __restrict__ A,
    const __bf16* __restrict__ Bt,
    TC* __restrict__ C,
    int M, int N, int K)
{
    __shared__ __bf16 As[128 * 32];   // [row][k]
    __shared__ __bf16 Bs[128 * 32];   // [col][k]

    const int tid  = threadIdx.x;
    const int wave = tid >> 6;
    const int lane = tid & 63;
    const int quad = lane >> 4;
    const int l15  = lane & 15;
    const int wr   = wave >> 1, wc = wave & 1;

    const int bm = blockIdx.y * 128;
    const int bn = blockIdx.x * 128;

    floatx4 acc[16];
    #pragma unroll
    for (int i = 0; i < 16; ++i) acc[i] = floatx4{0.f, 0.f, 0.f, 0.f};

    // staging: wave w covers rows w*32 .. w*32+31 of each tile (2 instrs)
    const __bf16* a0 = A  + (size_t)(bm + wave * 32 + (lane >> 2)) * K + (lane & 3) * 8;
    const __bf16* b0 = Bt + (size_t)(bn + wave * 32 + (lane >> 2)) * K + (lane & 3) * 8;
    __bf16* asd0 = As + (wave * 32) * 32;
    __bf16* asd1 = As + (wave * 32 + 16) * 32;
    __bf16* bsd0 = Bs + (wave * 32) * 32;
    __bf16* bsd1 = Bs + (wave * 32 + 16) * 32;

    for (int k0 = 0; k0 < K; k0 += 32) {
        __syncthreads();                       // previous tile's reads done
        async_cp16(a0 + k0,                asd0);
        async_cp16(a0 + (size_t)16 * K + k0, asd1);
        async_cp16(b0 + k0,                bsd0);
        async_cp16(b0 + (size_t)16 * K + k0, bsd1);
        __syncthreads();                       // loads drained (vmcnt before barrier)

        bf16x8 af[4], bf[4];
        #pragma unroll
        for (int t = 0; t < 4; ++t)
            af[t] = *(const bf16x8*)(&As[(wr * 64 + t * 16 + l15) * 32 + quad * 8]);
        #pragma unroll
        for (int u = 0; u < 4; ++u)
            bf[u] = *(const bf16x8*)(&Bs[(wc * 64 + u * 16 + l15) * 32 + quad * 8]);
        #pragma unroll
        for (int t = 0; t < 4; ++t)
            #pragma unroll
            for (int u = 0; u < 4; ++u)
                acc[t * 4 + u] = __builtin_amdgcn_mfma_f32_16x16x32_bf16(
                    af[t], bf[u], acc[t * 4 + u], 0, 0, 0);
    }

    #pragma unroll
    for (int t = 0; t < 4; ++t) {
        #pragma unroll
        for (int u = 0; u < 4; ++u) {
            #pragma unroll
            for (int r = 0; r < 4; ++r) {
                int row = bm + wr * 64 + t * 16 + quad * 4 + r;
                int col = bn + wc * 64 + u * 16 + l15;
                C[(size_t)row * N + col] = (TC)acc[t * 4 + u][r];
            }
        }
    }
}

// ---------------------------------------------------------------------------
// RoPE in-place on qkv [2048][6144]: heads 0..31 = q (col hi*128),
// heads 32..39 = k (col 4096 + (hi-32)*128). Rotate (j, j+64), angle n*10^-...
// ---------------------------------------------------------------------------
__global__ void rope_kernel(__bf16* __restrict__ qkv, int total)
{
    int idx = blockIdx.x * blockDim.x + threadIdx.x;
    if (idx >= total) return;
    int j    = idx & 63;
    int t    = idx >> 6;
    int head = t % 40;
    int row  = t / 40;
    int n    = row & 1023;

    int col0 = (head < 32) ? head * 128 : 4096 + (head - 32) * 128;

    float inv_freq = powf(10000.0f, -(float)j / 64.0f);
    float ang = (float)n * inv_freq;
    float c = cosf(ang), s = sinf(ang);

    size_t base = (size_t)row * 6144 + col0;
    float x1 = (float)qkv[base + j];
    float x2 = (float)qkv[base + 64 + j];
    qkv[base + j]      = (__bf16)(x1 * c - x2 * s);
    qkv[base + 64 + j] = (__bf16)(x1 * s + x2 * c);
}

// ---------------------------------------------------------------------------
// Causal flash attention, GQA-folded. Grid (16 qtiles, 16 bh), 512 thr/8 waves.
// Wave w: query-head instance i = w>>1, query half qh = w&1 (32 rows).
// qkv: [2048][6144] (q cols 0.., k cols 4096.., post-RoPE)
// vt : [16][128][1024] (V transposed per (b,h))
// ao : [2048][4096]  out cols (h*4+i)*128 + vd
// ---------------------------------------------------------------------------
__global__ __launch_bounds__(512, 2) void attn_kernel(
    const __bf16* __restrict__ qkv,
    const __bf16* __restrict__ vt,
    __bf16* __restrict__ ao)
{
    const int NSEQ = 1024, QLD = 6144, ALD = 4096;
    const int KS_LD = 136, VS_LD = 72, PS_LD = 72;
    __shared__ __bf16 Ks[64 * KS_LD];        // [key][kdim], padded
    __shared__ __bf16 Vs[128 * VS_LD];       // [vdim][key], padded
    __shared__ __bf16 Ps[8][32 * PS_LD];     // per-wave [qrow][key], padded

    const int tid  = threadIdx.x;
    const int wave = tid >> 6;
    const int lane = tid & 63;
    const int quad = lane >> 4;
    const int l15  = lane & 15;
    const int i    = wave >> 1;
    const int qh   = wave & 1;

    const int qb = blockIdx.x * 64;
    const int bh = blockIdx.y;
    const int b  = bh >> 3, h = bh & 7;
    const int qrow0 = qb + qh * 32;

    // Q fragments: qf[rowtile][c]
    bf16x8 qf[2][4];
    #pragma unroll
    for (int rt = 0; rt < 2; ++rt) {
        const __bf16* qp = qkv + (size_t)(b * NSEQ + qrow0 + rt * 16 + l15) * QLD
                               + (h * 4 + i) * 128;
        #pragma unroll
        for (int c = 0; c < 4; ++c)
            qf[rt][c] = *(const bf16x8*)(qp + c * 32 + quad * 8);
    }

    floatx4 acc[2][8];
    #pragma unroll
    for (int rt = 0; rt < 2; ++rt)
        #pragma unroll
        for (int u = 0; u < 8; ++u) acc[rt][u] = floatx4{0.f, 0.f, 0.f, 0.f};
    float m_run[2][4], l_run[2][4];
    #pragma unroll
    for (int rt = 0; rt < 2; ++rt)
        #pragma unroll
        for (int r = 0; r < 4; ++r) { m_run[rt][r] = NEG_BIG; l_run[rt][r] = 0.f; }

    const float scale = 0.08838834764831845f;   // 1/sqrt(128)
    const __bf16* vtb = vt + (size_t)bh * 128 * NSEQ;

    const int ntiles = blockIdx.x + 1;
    for (int tile = 0; tile < ntiles; ++tile) {
        const int kt = tile * 64;
        __syncthreads();   // previous tile's LDS reads done
        // stage K: 64 keys x 128 dims, vector loads+stores
        #pragma unroll
        for (int p = 0; p < 2; ++p) {
            int cch = tid + p * 512;             // 0..1023
            int key = cch >> 4, cg = (cch & 15) * 8;
            *(uint4*)(&Ks[key * KS_LD + cg]) = *(const uint4*)(
                qkv + (size_t)(b * NSEQ + kt + key) * QLD + 4096 + h * 128 + cg);
        }
        // stage V^T: 128 vdims x 64 keys, vector loads+stores
        #pragma unroll
        for (int p = 0; p < 2; ++p) {
            int cch = tid + p * 512;
            int vd = cch >> 3, kg = (cch & 7) * 8;
            *(uint4*)(&Vs[vd * VS_LD + kg]) = *(const uint4*)(
                vtb + (size_t)vd * NSEQ + kt + kg);
        }
        __syncthreads();

        // S = Q K^T  (2 rowtiles x 4 key-subtiles)
        floatx4 s[2][4];
        #pragma unroll
        for (int rt = 0; rt < 2; ++rt)
            #pragma unroll
            for (int ks = 0; ks < 4; ++ks) s[rt][ks] = floatx4{0.f, 0.f, 0.f, 0.f};
        #pragma unroll
        for (int ks = 0; ks < 4; ++ks) {
            #pragma unroll
            for (int c = 0; c < 4; ++c) {
                bf16x8 kf = *(const bf16x8*)(&Ks[(ks * 16 + l15) * KS_LD + c * 32 + quad * 8]);
                s[0][ks] = __builtin_amdgcn_mfma_f32_16x16x32_bf16(qf[0][c], kf, s[0][ks], 0, 0, 0);
                s[1][ks] = __builtin_amdgcn_mfma_f32_16x16x32_bf16(qf[1][c], kf, s[1][ks], 0, 0, 0);
            }
        }

        // online softmax (finite math)
        #pragma unroll
        for (int rt = 0; rt < 2; ++rt) {
            #pragma unroll
            for (int r = 0; r < 4; ++r) {
                int qrow = qrow0 + rt * 16 + quad * 4 + r;
                float v[4];
                #pragma unroll
                for (int ks = 0; ks < 4; ++ks) {
                    int kc = kt + ks * 16 + l15;
                    v[ks] = (kc <= qrow) ? s[rt][ks][r] * scale : NEG_BIG;
                }
                float m = fmaxf(fmaxf(v[0], v[1]), fmaxf(v[2], v[3]));
                #pragma unroll
                for (int off = 1; off < 16; off <<= 1)
                    m = fmaxf(m, __shfl_xor(m, off, 64));
                float mnew  = fmaxf(m_run[rt][r], m);
                float alpha = exp_safe(m_run[rt][r] - mnew);
                m_run[rt][r] = mnew;
                float p[4], srow = 0.f;
                #pragma unroll
                for (int ks = 0; ks < 4; ++ks) { p[ks] = exp_safe(v[ks] - mnew); srow += p[ks]; }
                #pragma unroll
                for (int off = 1; off < 16; off <<= 1)
                    srow += __shfl_xor(srow, off, 64);
                l_run[rt][r] = l_run[rt][r] * alpha + srow;
                int prow = rt * 16 + quad * 4 + r;
                #pragma unroll
                for (int ks = 0; ks < 4; ++ks)
                    Ps[wave][prow * PS_LD + ks * 16 + l15] = (__bf16)p[ks];
                #pragma unroll
                for (int u = 0; u < 8; ++u) acc[rt][u][r] *= alpha;
            }
        }
        // Ps is wave-private: no barrier needed before reading it back

        // O += P V   (2 k-steps of 32 keys)
        #pragma unroll
        for (int s2 = 0; s2 < 2; ++s2) {
            bf16x8 pa0 = *(const bf16x8*)(&Ps[wave][(l15)      * PS_LD + s2 * 32 + quad * 8]);
            bf16x8 pa1 = *(const bf16x8*)(&Ps[wave][(16 + l15) * PS_LD + s2 * 32 + quad * 8]);
            #pragma unroll
            for (int u = 0; u < 8; ++u) {
                bf16x8 vf = *(const bf16x8*)(&Vs[(u * 16 + l15) * VS_LD + s2 * 32 + quad * 8]);
                acc[0][u] = __builtin_amdgcn_mfma_f32_16x16x32_bf16(pa0, vf, acc[0][u], 0, 0, 0);
                acc[1][u] = __builtin_amdgcn_mfma_f32_16x16x32_bf16(pa1, vf, acc[1][u], 0, 0, 0);
            }
        }
    }

    // epilogue: normalize + store
    #pragma unroll
    for (int rt = 0; rt < 2; ++rt) {
        #pragma unroll
        for (int r = 0; r < 4; ++r) {
            float inv = 1.0f / l_run[rt][r];
            int row = qrow0 + rt * 16 + quad * 4 + r;
            __bf16* op = ao + (size_t)(b * NSEQ + row) * ALD + (h * 4 + i) * 128;
            #pragma unroll
            for (int u = 0; u < 8; ++u)
                op[u * 16 + l15] = (__bf16)(acc[rt][u][r] * inv);
        }
    }
}

// ---------------------------------------------------------------------------
extern "C" void kernel_launch(void* const* d_in, const int* in_sizes, int n_in,
                              void* d_out, int out_size, void* d_ws, size_t ws_size,
                              hipStream_t stream)
{
    const float* x  = (const float*)d_in[0];   // [2048][2048] fp32
    const float* Wq = (const float*)d_in[1];   // [2048][4096]
    const float* Wk = (const float*)d_in[2];   // [2048][1024]
    const float* Wv = (const float*)d_in[3];   // [2048][1024]
    const float* Wo = (const float*)d_in[4];   // [4096][2048]
    float* out = (float*)d_out;                // [2048][2048] fp32

    const size_t MB = 1024 * 1024;
    char* ws = (char*)d_ws;
    __bf16* qkv = (__bf16*)(ws);               // [2048][6144]  24 MB
    __bf16* vtb = (__bf16*)(ws + 24 * MB);     // [16][128][1024] 4 MB
    __bf16* xb  = (__bf16*)(ws + 28 * MB);     // [2048][2048]   8 MB
    __bf16* Wt  = (__bf16*)(ws + 36 * MB);     // [6144][2048]  24 MB (dead after GEMM1)
    __bf16* ao  = (__bf16*)(ws + 28 * MB);     // [2048][4096]  16 MB (reuses xb+Wt[0:8MB])
    __bf16* WoT = (__bf16*)(ws + 44 * MB);     // [2048][4096]  16 MB (reuses Wt[8:24MB])

    dim3 t32x8(32, 8);

    // 1) convert x -> bf16
    convert_kernel<<<2048, 256, 0, stream>>>(x, xb, 4194304 / 8);
    // 2) transpose-convert Wq/Wk/Wv into fused Bt [6144][2048]
    transpose_cvt_kernel<<<dim3(128, 64), t32x8, 0, stream>>>(Wq, Wt, 2048, 4096);
    transpose_cvt_kernel<<<dim3(32, 64),  t32x8, 0, stream>>>(Wk, Wt + (size_t)4096 * 2048, 2048, 1024);
    transpose_cvt_kernel<<<dim3(32, 64),  t32x8, 0, stream>>>(Wv, Wt + (size_t)5120 * 2048, 2048, 1024);
    // 3) fused QKV projection: qkv[2048][6144]
    gemm_bt<__bf16><<<dim3(48, 16), 256, 0, stream>>>(xb, Wt, qkv, 2048, 6144, 2048);
    // 4) Wo transpose-convert (after GEMM1: overwrites Wt region)
    transpose_cvt_kernel<<<dim3(64, 128), t32x8, 0, stream>>>(Wo, WoT, 4096, 2048);
    // 5) RoPE on q,k columns
    rope_kernel<<<(2048 * 40 * 64 + 255) / 256, 256, 0, stream>>>(qkv, 2048 * 40 * 64);
    // 6) V transpose into vt
    vtrans_kernel<<<dim3(32, 4, 16), t32x8, 0, stream>>>(qkv, vtb);
    // 7) attention
    attn_kernel<<<dim3(16, 16), 512, 0, stream>>>(qkv, vtb, ao);
    // 8) output projection
    gemm_bt<float><<<dim3(16, 16), 256, 0, stream>>>(ao, WoT, out, 2048, 2048, 4096);
}

// Round 5
// 337.706 us; speedup vs baseline: 2.6238x; 1.3148x over previous
//
#include <hip/hip_runtime.h>
#include <hip/hip_bf16.h>

typedef __bf16 bf16x8 __attribute__((ext_vector_type(8)));
typedef float floatx4 __attribute__((ext_vector_type(4)));

// async global->LDS, 16B per lane; LDS dst = wave-uniform base + lane*16
static __device__ __forceinline__ void async_cp16(const __bf16* g, __bf16* l) {
    typedef const __attribute__((address_space(1))) unsigned int gu32;
    typedef __attribute__((address_space(3))) unsigned int lu32;
    __builtin_amdgcn_global_load_lds((gu32*)g, (lu32*)l, 16, 0, 0);
}

// ---------------------------------------------------------------------------
// fp32 -> bf16 elementwise convert (n multiple of 8)
// ---------------------------------------------------------------------------
__global__ void convert_kernel(const float* __restrict__ src,
                               __bf16* __restrict__ dst, int n8)
{
    int idx = blockIdx.x * blockDim.x + threadIdx.x;
    if (idx >= n8) return;
    const float* p = src + (size_t)idx * 8;
    float4 f0 = *(const float4*)p;
    float4 f1 = *(const float4*)(p + 4);
    union { uint4 u; __bf16 b[8]; } o;
    o.b[0] = (__bf16)f0.x; o.b[1] = (__bf16)f0.y; o.b[2] = (__bf16)f0.z; o.b[3] = (__bf16)f0.w;
    o.b[4] = (__bf16)f1.x; o.b[5] = (__bf16)f1.y; o.b[6] = (__bf16)f1.z; o.b[7] = (__bf16)f1.w;
    *(uint4*)(dst + (size_t)idx * 8) = o.u;
}

// ---------------------------------------------------------------------------
// fp32 [R][C] -> bf16 [C][R] transpose-convert. Block (32,8), tile 32x32.
// ---------------------------------------------------------------------------
__global__ void transpose_cvt_kernel(const float* __restrict__ src,
                                     __bf16* __restrict__ dst, int R, int C)
{
    __shared__ float tile[32][33];
    const int tx = threadIdx.x, ty = threadIdx.y;
    const int c0 = blockIdx.x * 32, r0 = blockIdx.y * 32;
    #pragma unroll
    for (int j = 0; j < 4; ++j)
        tile[ty * 4 + j][tx] = src[(size_t)(r0 + ty * 4 + j) * C + c0 + tx];
    __syncthreads();
    #pragma unroll
    for (int j = 0; j < 4; ++j)
        dst[(size_t)(c0 + ty * 4 + j) * R + r0 + tx] = (__bf16)tile[tx][ty * 4 + j];
}

// ---------------------------------------------------------------------------
// bf16 transpose of the V columns of qkv into vt[b*8+h][128][1024].
// ---------------------------------------------------------------------------
__global__ void vtrans_kernel(const __bf16* __restrict__ qkv,
                              __bf16* __restrict__ vt)
{
    __shared__ __bf16 tile[32][33];
    const int tx = threadIdx.x, ty = threadIdx.y;
    const int k0 = blockIdx.x * 32, v0 = blockIdx.y * 32;
    const int bh = blockIdx.z;
    const int b = bh >> 3, h = bh & 7;
    #pragma unroll
    for (int j = 0; j < 4; ++j)
        tile[ty * 4 + j][tx] =
            qkv[(size_t)(b * 1024 + k0 + ty * 4 + j) * 6144 + 5120 + h * 128 + v0 + tx];
    __syncthreads();
    #pragma unroll
    for (int j = 0; j < 4; ++j)
        vt[((size_t)bh * 128 + v0 + ty * 4 + j) * 1024 + k0 + tx] = tile[tx][ty * 4 + j];
}

// ---------------------------------------------------------------------------
// GEMM (m97): C[M][N] = A[M][K] * Bt[N][K]^T. Tile 128x128, BK=32, DMA staging.
// ---------------------------------------------------------------------------
template <typename TC>
__global__ __launch_bounds__(256) void gemm_bt(
    const __bf16* __restrict__ A,
    const __bf16* __restrict__ Bt,
    TC* __restrict__ C,
    int M, int N, int K)
{
    __shared__ __bf16 As[128 * 32];
    __shared__ __bf16 Bs[128 * 32];

    const int tid  = threadIdx.x;
    const int wave = tid >> 6;
    const int lane = tid & 63;
    const int quad = lane >> 4;
    const int l15  = lane & 15;
    const int wr   = wave >> 1, wc = wave & 1;

    const int bm = blockIdx.y * 128;
    const int bn = blockIdx.x * 128;

    floatx4 acc[16];
    #pragma unroll
    for (int i = 0; i < 16; ++i) acc[i] = floatx4{0.f, 0.f, 0.f, 0.f};

    const __bf16* a0 = A  + (size_t)(bm + wave * 32 + (lane >> 2)) * K + (lane & 3) * 8;
    const __bf16* b0 = Bt + (size_t)(bn + wave * 32 + (lane >> 2)) * K + (lane & 3) * 8;
    __bf16* asd0 = As + (wave * 32) * 32;
    __bf16* asd1 = As + (wave * 32 + 16) * 32;
    __bf16* bsd0 = Bs + (wave * 32) * 32;
    __bf16* bsd1 = Bs + (wave * 32 + 16) * 32;

    for (int k0 = 0; k0 < K; k0 += 32) {
        __syncthreads();
        async_cp16(a0 + k0,                  asd0);
        async_cp16(a0 + (size_t)16 * K + k0, asd1);
        async_cp16(b0 + k0,                  bsd0);
        async_cp16(b0 + (size_t)16 * K + k0, bsd1);
        __syncthreads();

        bf16x8 af[4], bf[4];
        #pragma unroll
        for (int t = 0; t < 4; ++t)
            af[t] = *(const bf16x8*)(&As[(wr * 64 + t * 16 + l15) * 32 + quad * 8]);
        #pragma unroll
        for (int u = 0; u < 4; ++u)
            bf[u] = *(const bf16x8*)(&Bs[(wc * 64 + u * 16 + l15) * 32 + quad * 8]);
        #pragma unroll
        for (int t = 0; t < 4; ++t)
            #pragma unroll
            for (int u = 0; u < 4; ++u)
                acc[t * 4 + u] = __builtin_amdgcn_mfma_f32_16x16x32_bf16(
                    af[t], bf[u], acc[t * 4 + u], 0, 0, 0);
    }

    #pragma unroll
    for (int t = 0; t < 4; ++t)
        #pragma unroll
        for (int u = 0; u < 4; ++u)
            #pragma unroll
            for (int r = 0; r < 4; ++r) {
                int row = bm + wr * 64 + t * 16 + quad * 4 + r;
                int col = bn + wc * 64 + u * 16 + l15;
                C[(size_t)row * N + col] = (TC)acc[t * 4 + u][r];
            }
}

// ---------------------------------------------------------------------------
// GEMM tile 128x64 (for 2048x2048 output -> 512 blocks, 2/CU). BK=32.
// Waves 2x2, each 64 rows x 32 cols.
// ---------------------------------------------------------------------------
template <typename TC>
__global__ __launch_bounds__(256) void gemm_bt64(
    const __bf16* __restrict__ A,
    const __bf16* __restrict__ Bt,
    TC* __restrict__ C,
    int M, int N, int K)
{
    __shared__ __bf16 As[128 * 32];
    __shared__ __bf16 Bs[64 * 32];

    const int tid  = threadIdx.x;
    const int wave = tid >> 6;
    const int lane = tid & 63;
    const int quad = lane >> 4;
    const int l15  = lane & 15;
    const int wr   = wave >> 1, wc = wave & 1;

    const int bm = blockIdx.y * 128;
    const int bn = blockIdx.x * 64;

    floatx4 acc[8];
    #pragma unroll
    for (int i = 0; i < 8; ++i) acc[i] = floatx4{0.f, 0.f, 0.f, 0.f};

    const __bf16* a0 = A  + (size_t)(bm + wave * 32 + (lane >> 2)) * K + (lane & 3) * 8;
    const __bf16* b0 = Bt + (size_t)(bn + wave * 16 + (lane >> 2)) * K + (lane & 3) * 8;
    __bf16* asd0 = As + (wave * 32) * 32;
    __bf16* asd1 = As + (wave * 32 + 16) * 32;
    __bf16* bsd0 = Bs + (wave * 16) * 32;

    for (int k0 = 0; k0 < K; k0 += 32) {
        __syncthreads();
        async_cp16(a0 + k0,                  asd0);
        async_cp16(a0 + (size_t)16 * K + k0, asd1);
        async_cp16(b0 + k0,                  bsd0);
        __syncthreads();

        bf16x8 af[4], bf[2];
        #pragma unroll
        for (int t = 0; t < 4; ++t)
            af[t] = *(const bf16x8*)(&As[(wr * 64 + t * 16 + l15) * 32 + quad * 8]);
        #pragma unroll
        for (int u = 0; u < 2; ++u)
            bf[u] = *(const bf16x8*)(&Bs[(wc * 32 + u * 16 + l15) * 32 + quad * 8]);
        #pragma unroll
        for (int t = 0; t < 4; ++t)
            #pragma unroll
            for (int u = 0; u < 2; ++u)
                acc[t * 2 + u] = __builtin_amdgcn_mfma_f32_16x16x32_bf16(
                    af[t], bf[u], acc[t * 2 + u], 0, 0, 0);
    }

    #pragma unroll
    for (int t = 0; t < 4; ++t)
        #pragma unroll
        for (int u = 0; u < 2; ++u)
            #pragma unroll
            for (int r = 0; r < 4; ++r) {
                int row = bm + wr * 64 + t * 16 + quad * 4 + r;
                int col = bn + wc * 32 + u * 16 + l15;
                C[(size_t)row * N + col] = (TC)acc[t * 2 + u][r];
            }
}

// ---------------------------------------------------------------------------
// RoPE in-place on qkv [2048][6144], vectorized: thread = (row, head, 8 js).
// ---------------------------------------------------------------------------
__global__ void rope_kernel(__bf16* __restrict__ qkv, int total)
{
    int idx = blockIdx.x * blockDim.x + threadIdx.x;
    if (idx >= total) return;
    int part = idx & 7;
    int t    = idx >> 3;
    int head = t % 40;
    int row  = t / 40;
    int n    = row & 1023;

    int col0 = (head < 32) ? head * 128 : 4096 + (head - 32) * 128;
    size_t base = (size_t)row * 6144 + col0 + part * 8;

    union { uint4 u; __bf16 b[8]; } x1, x2, o1, o2;
    x1.u = *(const uint4*)(qkv + base);
    x2.u = *(const uint4*)(qkv + base + 64);
    #pragma unroll
    for (int e = 0; e < 8; ++e) {
        int j = part * 8 + e;
        float inv_freq = exp2f(-(float)j * 0.20762050593046015f); // log2(1e4)/64
        float ang = (float)n * inv_freq;
        float sv, cv;
        __sincosf(ang, &sv, &cv);
        float a = (float)x1.b[e], b2 = (float)x2.b[e];
        o1.b[e] = (__bf16)(a * cv - b2 * sv);
        o2.b[e] = (__bf16)(a * sv + b2 * cv);
    }
    *(uint4*)(qkv + base)      = o1.u;
    *(uint4*)(qkv + base + 64) = o2.u;
}

// ---------------------------------------------------------------------------
// Causal flash attention, balanced pairing + max-free softmax + DMA staging.
// Grid (16 pairs, 16 bh), 512 thr / 8 waves (4 i x 2 rt of 16 q-rows).
// Block handles q-tiles pair p and 31-p (32 rows each) serially:
// total k-tiles = 17, identical for every block.
// Ks/Vs: XOR-swizzled unpadded LDS, staged via global_load_lds width-16.
//   Ks slot(key, c) = c ^ (key & 15)   (16 chunks of 16B per key row)
//   Vs slot(vd,  c) = c ^ (vd  & 7)    (8 chunks of 16B per vdim row)
// Softmax: no running max (scores provably bounded); l via ones-MFMA.
// ---------------------------------------------------------------------------
__global__ __launch_bounds__(512, 2) void attn_kernel(
    const __bf16* __restrict__ qkv,
    const __bf16* __restrict__ vt,
    __bf16* __restrict__ ao)
{
    const int PS_LD = 72;
    __shared__ __bf16 Ks[64 * 128];      // [key][kdim], swizzled
    __shared__ __bf16 Vs[128 * 64];      // [vdim][key], swizzled
    __shared__ __bf16 Ps[8][16 * PS_LD]; // per-wave [qrow][key], padded

    const int tid  = threadIdx.x;
    const int wave = tid >> 6;
    const int lane = tid & 63;
    const int quad = lane >> 4;
    const int l15  = lane & 15;
    const int i    = wave >> 1;
    const int rt   = wave & 1;

    const int pair = blockIdx.x;
    const int bh   = blockIdx.y;
    const int b    = bh >> 3, h = bh & 7;
    const __bf16* vtb = vt + (size_t)bh * 128 * 1024;

    // staging addresses (per-lane global, wave-uniform LDS)
    const int keyA = wave * 8 + (lane >> 4);           // instr0: 4 keys/wave
    const int keyB = keyA + 4;
    const int chA  = (lane & 15) ^ (keyA & 15);
    const int chB  = (lane & 15) ^ (keyB & 15);
    const __bf16* gK0 = qkv + (size_t)(b * 1024 + keyA) * 6144 + 4096 + h * 128 + chA * 8;
    const __bf16* gK1 = qkv + (size_t)(b * 1024 + keyB) * 6144 + 4096 + h * 128 + chB * 8;
    __bf16* lK0 = Ks + (wave * 8) * 128;
    __bf16* lK1 = Ks + (wave * 8 + 4) * 128;

    const int vdA = wave * 16 + (lane >> 3);           // instr0: 8 vdims/wave
    const int vdB = vdA + 8;
    const int cvA = (lane & 7) ^ (vdA & 7);
    const int cvB = (lane & 7) ^ (vdB & 7);
    const __bf16* gV0 = vtb + (size_t)vdA * 1024 + cvA * 8;
    const __bf16* gV1 = vtb + (size_t)vdB * 1024 + cvB * 8;
    __bf16* lV0 = Vs + (wave * 16) * 64;
    __bf16* lV1 = Vs + (wave * 16 + 8) * 64;

    bf16x8 onesf;
    #pragma unroll
    for (int j = 0; j < 8; ++j) onesf[j] = (__bf16)1.0f;

    const float C2 = 0.12751898549f;   // (1/sqrt(128)) * log2(e)

    #pragma unroll
    for (int ph = 0; ph < 2; ++ph) {
        const int qt    = ph ? (31 - pair) : pair;
        const int qrow0 = qt * 32 + rt * 16;

        // Q fragments
        const __bf16* qp = qkv + (size_t)(b * 1024 + qrow0 + l15) * 6144 + (h * 4 + i) * 128;
        bf16x8 qf[4];
        #pragma unroll
        for (int c = 0; c < 4; ++c)
            qf[c] = *(const bf16x8*)(qp + c * 32 + quad * 8);

        floatx4 acc[8];
        #pragma unroll
        for (int u = 0; u < 8; ++u) acc[u] = floatx4{0.f, 0.f, 0.f, 0.f};
        floatx4 accl = floatx4{0.f, 0.f, 0.f, 0.f};

        const int ntiles = (qt >> 1) + 1;
        for (int t = 0; t < ntiles; ++t) {
            const int kt = t * 64;
            __syncthreads();   // all waves done with previous Ks/Vs
            async_cp16(gK0 + (size_t)kt * 6144, lK0);
            async_cp16(gK1 + (size_t)kt * 6144, lK1);
            async_cp16(gV0 + kt, lV0);
            async_cp16(gV1 + kt, lV1);
            __syncthreads();   // DMA drained

            // S = Q K^T
            floatx4 s[4];
            #pragma unroll
            for (int ks = 0; ks < 4; ++ks) s[ks] = floatx4{0.f, 0.f, 0.f, 0.f};
            #pragma unroll
            for (int c = 0; c < 4; ++c) {
                #pragma unroll
                for (int ks = 0; ks < 4; ++ks) {
                    bf16x8 kf = *(const bf16x8*)(
                        &Ks[(ks * 16 + l15) * 128 + ((c * 4 + quad) ^ l15) * 8]);
                    s[ks] = __builtin_amdgcn_mfma_f32_16x16x32_bf16(qf[c], kf, s[ks], 0, 0, 0);
                }
            }

            // max-free softmax: p = exp2(s*C2), masked -> 0
            #pragma unroll
            for (int r = 0; r < 4; ++r) {
                int qrow = qrow0 + quad * 4 + r;
                #pragma unroll
                for (int ks = 0; ks < 4; ++ks) {
                    int kc = kt + ks * 16 + l15;
                    float p = (kc <= qrow) ? exp2f(s[ks][r] * C2) : 0.0f;
                    Ps[wave][(quad * 4 + r) * PS_LD + ks * 16 + l15] = (__bf16)p;
                }
            }

            // O += P V ; l += P * ones   (Ps is wave-private: no barrier)
            #pragma unroll
            for (int s2 = 0; s2 < 2; ++s2) {
                bf16x8 pa = *(const bf16x8*)(&Ps[wave][l15 * PS_LD + s2 * 32 + quad * 8]);
                accl = __builtin_amdgcn_mfma_f32_16x16x32_bf16(pa, onesf, accl, 0, 0, 0);
                #pragma unroll
                for (int u = 0; u < 8; ++u) {
                    bf16x8 vf = *(const bf16x8*)(
                        &Vs[(u * 16 + l15) * 64 + (((s2 * 4 + quad) ^ (l15 & 7))) * 8]);
                    acc[u] = __builtin_amdgcn_mfma_f32_16x16x32_bf16(pa, vf, acc[u], 0, 0, 0);
                }
            }
        }

        // epilogue
        #pragma unroll
        for (int r = 0; r < 4; ++r) {
            float inv = 1.0f / accl[r];
            int row = qrow0 + quad * 4 + r;
            __bf16* op = ao + (size_t)(b * 1024 + row) * 4096 + (h * 4 + i) * 128;
            #pragma unroll
            for (int u = 0; u < 8; ++u)
                op[u * 16 + l15] = (__bf16)(acc[u][r] * inv);
        }
    }
}

// ---------------------------------------------------------------------------
extern "C" void kernel_launch(void* const* d_in, const int* in_sizes, int n_in,
                              void* d_out, int out_size, void* d_ws, size_t ws_size,
                              hipStream_t stream)
{
    const float* x  = (const float*)d_in[0];   // [2048][2048]
    const float* Wq = (const float*)d_in[1];   // [2048][4096]
    const float* Wk = (const float*)d_in[2];   // [2048][1024]
    const float* Wv = (const float*)d_in[3];   // [2048][1024]
    const float* Wo = (const float*)d_in[4];   // [4096][2048]
    float* out = (float*)d_out;                // [2048][2048]

    const size_t MB = 1024 * 1024;
    char* ws = (char*)d_ws;
    __bf16* qkv = (__bf16*)(ws);               // [2048][6144]    24 MB
    __bf16* vtb = (__bf16*)(ws + 24 * MB);     // [16][128][1024]  4 MB
    __bf16* xb  = (__bf16*)(ws + 28 * MB);     // [2048][2048]     8 MB
    __bf16* Wt  = (__bf16*)(ws + 36 * MB);     // [6144][2048]    24 MB (dead after GEMM1)
    __bf16* ao  = (__bf16*)(ws + 28 * MB);     // [2048][4096]    16 MB (reuses xb + Wt[0:8])
    __bf16* WoT = (__bf16*)(ws + 44 * MB);     // [2048][4096]    16 MB (reuses Wt[8:24])

    dim3 t32x8(32, 8);

    convert_kernel<<<2048, 256, 0, stream>>>(x, xb, 4194304 / 8);
    transpose_cvt_kernel<<<dim3(128, 64), t32x8, 0, stream>>>(Wq, Wt, 2048, 4096);
    transpose_cvt_kernel<<<dim3(32, 64),  t32x8, 0, stream>>>(Wk, Wt + (size_t)4096 * 2048, 2048, 1024);
    transpose_cvt_kernel<<<dim3(32, 64),  t32x8, 0, stream>>>(Wv, Wt + (size_t)5120 * 2048, 2048, 1024);
    gemm_bt<__bf16><<<dim3(48, 16), 256, 0, stream>>>(xb, Wt, qkv, 2048, 6144, 2048);
    transpose_cvt_kernel<<<dim3(64, 128), t32x8, 0, stream>>>(Wo, WoT, 4096, 2048);
    rope_kernel<<<(2048 * 40 * 8 + 255) / 256, 256, 0, stream>>>(qkv, 2048 * 40 * 8);
    vtrans_kernel<<<dim3(32, 4, 16), t32x8, 0, stream>>>(qkv, vtb);
    attn_kernel<<<dim3(16, 16), 512, 0, stream>>>(qkv, vtb, ao);
    gemm_bt64<float><<<dim3(32, 16), 256, 0, stream>>>(ao, WoT, out, 2048, 2048, 4096);
}

// Round 6
// 323.532 us; speedup vs baseline: 2.7388x; 1.0438x over previous
//
#include <hip/hip_runtime.h>
#include <hip/hip_bf16.h>

typedef __bf16 bf16x8 __attribute__((ext_vector_type(8)));
typedef float floatx4 __attribute__((ext_vector_type(4)));

// async global->LDS, 16B per lane; LDS dst = wave-uniform base + lane*16
static __device__ __forceinline__ void async_cp16(const __bf16* g, __bf16* l) {
    typedef const __attribute__((address_space(1))) unsigned int gu32;
    typedef __attribute__((address_space(3))) unsigned int lu32;
    __builtin_amdgcn_global_load_lds((gu32*)g, (lu32*)l, 16, 0, 0);
}

// ---------------------------------------------------------------------------
// Fused prep: blocks [0,8192) transpose Wq; [8192,10240) Wk; [10240,12288) Wv;
// [12288,14336) convert x -> bf16. All 256-thread blocks.
// ---------------------------------------------------------------------------
__global__ __launch_bounds__(256) void prep_kernel(
    const float* __restrict__ x,  __bf16* __restrict__ xb,
    const float* __restrict__ Wq, const float* __restrict__ Wk,
    const float* __restrict__ Wv, __bf16* __restrict__ Wt)
{
    __shared__ float tile[32][33];
    const int bk  = blockIdx.x;
    const int tid = threadIdx.x;
    const int tx  = tid & 31, ty = tid >> 5;

    if (bk < 12288) {
        const float* src; __bf16* dst; int R = 2048, C; int bxx, byy;
        if (bk < 8192)        { src = Wq; dst = Wt;                          C = 4096; bxx = bk & 127;           byy = bk >> 7; }
        else if (bk < 10240)  { src = Wk; dst = Wt + (size_t)4096 * 2048;    C = 1024; bxx = (bk - 8192) & 31;   byy = (bk - 8192) >> 5; }
        else                  { src = Wv; dst = Wt + (size_t)5120 * 2048;    C = 1024; bxx = (bk - 10240) & 31;  byy = (bk - 10240) >> 5; }
        const int c0 = bxx * 32, r0 = byy * 32;
        #pragma unroll
        for (int j = 0; j < 4; ++j)
            tile[ty * 4 + j][tx] = src[(size_t)(r0 + ty * 4 + j) * C + c0 + tx];
        __syncthreads();
        #pragma unroll
        for (int j = 0; j < 4; ++j)
            dst[(size_t)(c0 + ty * 4 + j) * R + r0 + tx] = (__bf16)tile[tx][ty * 4 + j];
    } else {
        int idx = (bk - 12288) * 256 + tid;          // 8 elems each, 4.19M total
        const float* p = x + (size_t)idx * 8;
        float4 f0 = *(const float4*)p;
        float4 f1 = *(const float4*)(p + 4);
        union { uint4 u; __bf16 b[8]; } o;
        o.b[0] = (__bf16)f0.x; o.b[1] = (__bf16)f0.y; o.b[2] = (__bf16)f0.z; o.b[3] = (__bf16)f0.w;
        o.b[4] = (__bf16)f1.x; o.b[5] = (__bf16)f1.y; o.b[6] = (__bf16)f1.z; o.b[7] = (__bf16)f1.w;
        *(uint4*)(xb + (size_t)idx * 8) = o.u;
    }
}

// ---------------------------------------------------------------------------
// fp32 [R][C] -> bf16 [C][R] transpose-convert (for Wo, after GEMM1).
// ---------------------------------------------------------------------------
__global__ void transpose_cvt_kernel(const float* __restrict__ src,
                                     __bf16* __restrict__ dst, int R, int C)
{
    __shared__ float tile[32][33];
    const int tx = threadIdx.x, ty = threadIdx.y;
    const int c0 = blockIdx.x * 32, r0 = blockIdx.y * 32;
    #pragma unroll
    for (int j = 0; j < 4; ++j)
        tile[ty * 4 + j][tx] = src[(size_t)(r0 + ty * 4 + j) * C + c0 + tx];
    __syncthreads();
    #pragma unroll
    for (int j = 0; j < 4; ++j)
        dst[(size_t)(c0 + ty * 4 + j) * R + r0 + tx] = (__bf16)tile[tx][ty * 4 + j];
}

// ---------------------------------------------------------------------------
// Fused RoPE + V-transpose. Blocks [0,2560): rope; [2560,4608): vtrans.
// ---------------------------------------------------------------------------
__global__ __launch_bounds__(256) void rope_vtrans_kernel(
    __bf16* __restrict__ qkv, __bf16* __restrict__ vt)
{
    __shared__ __bf16 tile[32][33];
    const int bk  = blockIdx.x;
    const int tid = threadIdx.x;

    if (bk < 2560) {
        int idx  = bk * 256 + tid;       // 655360 total
        int part = idx & 7;
        int t    = idx >> 3;
        int head = t % 40;
        int row  = t / 40;
        int n    = row & 1023;
        int col0 = (head < 32) ? head * 128 : 4096 + (head - 32) * 128;
        size_t base = (size_t)row * 6144 + col0 + part * 8;

        union { uint4 u; __bf16 b[8]; } x1, x2, o1, o2;
        x1.u = *(const uint4*)(qkv + base);
        x2.u = *(const uint4*)(qkv + base + 64);
        #pragma unroll
        for (int e = 0; e < 8; ++e) {
            int j = part * 8 + e;
            float inv_freq = exp2f(-(float)j * 0.20762050593046015f); // log2(1e4)/64
            float ang = (float)n * inv_freq;
            float sv, cv;
            __sincosf(ang, &sv, &cv);
            float a = (float)x1.b[e], b2 = (float)x2.b[e];
            o1.b[e] = (__bf16)(a * cv - b2 * sv);
            o2.b[e] = (__bf16)(a * sv + b2 * cv);
        }
        *(uint4*)(qkv + base)      = o1.u;
        *(uint4*)(qkv + base + 64) = o2.u;
    } else {
        int idx = bk - 2560;             // 2048 blocks
        const int tx = tid & 31, ty = tid >> 5;
        const int k0 = (idx & 31) * 32;
        const int v0 = ((idx >> 5) & 3) * 32;
        const int bh = idx >> 7;
        const int b = bh >> 3, h = bh & 7;
        #pragma unroll
        for (int j = 0; j < 4; ++j)
            tile[ty * 4 + j][tx] =
                qkv[(size_t)(b * 1024 + k0 + ty * 4 + j) * 6144 + 5120 + h * 128 + v0 + tx];
        __syncthreads();
        #pragma unroll
        for (int j = 0; j < 4; ++j)
            vt[((size_t)bh * 128 + v0 + ty * 4 + j) * 1024 + k0 + tx] = tile[tx][ty * 4 + j];
    }
}

// ---------------------------------------------------------------------------
// GEMM (m97): C[z][M][N] = A[.][koff..] * Bt[.][koff..]^T, koff = z*Kc.
// Tile 128x128, BK=32, DMA staging. lda/ldb/ldc allow split-K (gridDim.z>1).
// ---------------------------------------------------------------------------
template <typename TC>
__global__ __launch_bounds__(256) void gemm_bt(
    const __bf16* __restrict__ A,
    const __bf16* __restrict__ Bt,
    TC* __restrict__ C,
    int M, int N, int Kc, int lda, int ldb, int ldc)
{
    __shared__ __bf16 As[128 * 32];
    __shared__ __bf16 Bs[128 * 32];

    const int tid  = threadIdx.x;
    const int wave = tid >> 6;
    const int lane = tid & 63;
    const int quad = lane >> 4;
    const int l15  = lane & 15;
    const int wr   = wave >> 1, wc = wave & 1;

    const int bm = blockIdx.y * 128;
    const int bn = blockIdx.x * 128;
    const int z  = blockIdx.z;

    A  += (size_t)z * Kc;
    Bt += (size_t)z * Kc;
    C  += (size_t)z * M * ldc;

    floatx4 acc[16];
    #pragma unroll
    for (int i = 0; i < 16; ++i) acc[i] = floatx4{0.f, 0.f, 0.f, 0.f};

    const __bf16* a0 = A  + (size_t)(bm + wave * 32 + (lane >> 2)) * lda + (lane & 3) * 8;
    const __bf16* b0 = Bt + (size_t)(bn + wave * 32 + (lane >> 2)) * ldb + (lane & 3) * 8;
    __bf16* asd0 = As + (wave * 32) * 32;
    __bf16* asd1 = As + (wave * 32 + 16) * 32;
    __bf16* bsd0 = Bs + (wave * 32) * 32;
    __bf16* bsd1 = Bs + (wave * 32 + 16) * 32;

    for (int k0 = 0; k0 < Kc; k0 += 32) {
        __syncthreads();
        async_cp16(a0 + k0,                    asd0);
        async_cp16(a0 + (size_t)16 * lda + k0, asd1);
        async_cp16(b0 + k0,                    bsd0);
        async_cp16(b0 + (size_t)16 * ldb + k0, bsd1);
        __syncthreads();

        bf16x8 af[4], bf[4];
        #pragma unroll
        for (int t = 0; t < 4; ++t)
            af[t] = *(const bf16x8*)(&As[(wr * 64 + t * 16 + l15) * 32 + quad * 8]);
        #pragma unroll
        for (int u = 0; u < 4; ++u)
            bf[u] = *(const bf16x8*)(&Bs[(wc * 64 + u * 16 + l15) * 32 + quad * 8]);
        #pragma unroll
        for (int t = 0; t < 4; ++t)
            #pragma unroll
            for (int u = 0; u < 4; ++u)
                acc[t * 4 + u] = __builtin_amdgcn_mfma_f32_16x16x32_bf16(
                    af[t], bf[u], acc[t * 4 + u], 0, 0, 0);
    }

    #pragma unroll
    for (int t = 0; t < 4; ++t)
        #pragma unroll
        for (int u = 0; u < 4; ++u)
            #pragma unroll
            for (int r = 0; r < 4; ++r) {
                int row = bm + wr * 64 + t * 16 + quad * 4 + r;
                int col = bn + wc * 64 + u * 16 + l15;
                C[(size_t)row * ldc + col] = (TC)acc[t * 4 + u][r];
            }
}

// ---------------------------------------------------------------------------
// Split-K reduce: out[i] = part[0][i] + part[1][i]  (bf16 partials, fp32 out)
// ---------------------------------------------------------------------------
__global__ __launch_bounds__(256) void reduce_kernel(
    const __bf16* __restrict__ part, float* __restrict__ out)
{
    int idx = blockIdx.x * 256 + threadIdx.x;      // 8 elems each
    const size_t STRIDE = (size_t)2048 * 2048;
    union { uint4 u; __bf16 b[8]; } p0, p1;
    p0.u = *(const uint4*)(part + (size_t)idx * 8);
    p1.u = *(const uint4*)(part + STRIDE + (size_t)idx * 8);
    float4 o0, o1;
    o0.x = (float)p0.b[0] + (float)p1.b[0];
    o0.y = (float)p0.b[1] + (float)p1.b[1];
    o0.z = (float)p0.b[2] + (float)p1.b[2];
    o0.w = (float)p0.b[3] + (float)p1.b[3];
    o1.x = (float)p0.b[4] + (float)p1.b[4];
    o1.y = (float)p0.b[5] + (float)p1.b[5];
    o1.z = (float)p0.b[6] + (float)p1.b[6];
    o1.w = (float)p0.b[7] + (float)p1.b[7];
    *(float4*)(out + (size_t)idx * 8)     = o0;
    *(float4*)(out + (size_t)idx * 8 + 4) = o1;
}

// ---------------------------------------------------------------------------
// Causal flash attention (unchanged from R5: balanced pairing, max-free
// softmax, swizzled DMA staging).
// ---------------------------------------------------------------------------
__global__ __launch_bounds__(512, 2) void attn_kernel(
    const __bf16* __restrict__ qkv,
    const __bf16* __restrict__ vt,
    __bf16* __restrict__ ao)
{
    const int PS_LD = 72;
    __shared__ __bf16 Ks[64 * 128];      // [key][kdim], swizzled
    __shared__ __bf16 Vs[128 * 64];      // [vdim][key], swizzled
    __shared__ __bf16 Ps[8][16 * PS_LD]; // per-wave [qrow][key], padded

    const int tid  = threadIdx.x;
    const int wave = tid >> 6;
    const int lane = tid & 63;
    const int quad = lane >> 4;
    const int l15  = lane & 15;
    const int i    = wave >> 1;
    const int rt   = wave & 1;

    const int pair = blockIdx.x;
    const int bh   = blockIdx.y;
    const int b    = bh >> 3, h = bh & 7;
    const __bf16* vtb = vt + (size_t)bh * 128 * 1024;

    const int keyA = wave * 8 + (lane >> 4);
    const int keyB = keyA + 4;
    const int chA  = (lane & 15) ^ (keyA & 15);
    const int chB  = (lane & 15) ^ (keyB & 15);
    const __bf16* gK0 = qkv + (size_t)(b * 1024 + keyA) * 6144 + 4096 + h * 128 + chA * 8;
    const __bf16* gK1 = qkv + (size_t)(b * 1024 + keyB) * 6144 + 4096 + h * 128 + chB * 8;
    __bf16* lK0 = Ks + (wave * 8) * 128;
    __bf16* lK1 = Ks + (wave * 8 + 4) * 128;

    const int vdA = wave * 16 + (lane >> 3);
    const int vdB = vdA + 8;
    const int cvA = (lane & 7) ^ (vdA & 7);
    const int cvB = (lane & 7) ^ (vdB & 7);
    const __bf16* gV0 = vtb + (size_t)vdA * 1024 + cvA * 8;
    const __bf16* gV1 = vtb + (size_t)vdB * 1024 + cvB * 8;
    __bf16* lV0 = Vs + (wave * 16) * 64;
    __bf16* lV1 = Vs + (wave * 16 + 8) * 64;

    bf16x8 onesf;
    #pragma unroll
    for (int j = 0; j < 8; ++j) onesf[j] = (__bf16)1.0f;

    const float C2 = 0.12751898549f;   // (1/sqrt(128)) * log2(e)

    #pragma unroll
    for (int ph = 0; ph < 2; ++ph) {
        const int qt    = ph ? (31 - pair) : pair;
        const int qrow0 = qt * 32 + rt * 16;

        const __bf16* qp = qkv + (size_t)(b * 1024 + qrow0 + l15) * 6144 + (h * 4 + i) * 128;
        bf16x8 qf[4];
        #pragma unroll
        for (int c = 0; c < 4; ++c)
            qf[c] = *(const bf16x8*)(qp + c * 32 + quad * 8);

        floatx4 acc[8];
        #pragma unroll
        for (int u = 0; u < 8; ++u) acc[u] = floatx4{0.f, 0.f, 0.f, 0.f};
        floatx4 accl = floatx4{0.f, 0.f, 0.f, 0.f};

        const int ntiles = (qt >> 1) + 1;
        for (int t = 0; t < ntiles; ++t) {
            const int kt = t * 64;
            __syncthreads();
            async_cp16(gK0 + (size_t)kt * 6144, lK0);
            async_cp16(gK1 + (size_t)kt * 6144, lK1);
            async_cp16(gV0 + kt, lV0);
            async_cp16(gV1 + kt, lV1);
            __syncthreads();

            floatx4 s[4];
            #pragma unroll
            for (int ks = 0; ks < 4; ++ks) s[ks] = floatx4{0.f, 0.f, 0.f, 0.f};
            #pragma unroll
            for (int c = 0; c < 4; ++c) {
                #pragma unroll
                for (int ks = 0; ks < 4; ++ks) {
                    bf16x8 kf = *(const bf16x8*)(
                        &Ks[(ks * 16 + l15) * 128 + ((c * 4 + quad) ^ l15) * 8]);
                    s[ks] = __builtin_amdgcn_mfma_f32_16x16x32_bf16(qf[c], kf, s[ks], 0, 0, 0);
                }
            }

            #pragma unroll
            for (int r = 0; r < 4; ++r) {
                int qrow = qrow0 + quad * 4 + r;
                #pragma unroll
                for (int ks = 0; ks < 4; ++ks) {
                    int kc = kt + ks * 16 + l15;
                    float p = (kc <= qrow) ? exp2f(s[ks][r] * C2) : 0.0f;
                    Ps[wave][(quad * 4 + r) * PS_LD + ks * 16 + l15] = (__bf16)p;
                }
            }

            #pragma unroll
            for (int s2 = 0; s2 < 2; ++s2) {
                bf16x8 pa = *(const bf16x8*)(&Ps[wave][l15 * PS_LD + s2 * 32 + quad * 8]);
                accl = __builtin_amdgcn_mfma_f32_16x16x32_bf16(pa, onesf, accl, 0, 0, 0);
                #pragma unroll
                for (int u = 0; u < 8; ++u) {
                    bf16x8 vf = *(const bf16x8*)(
                        &Vs[(u * 16 + l15) * 64 + (((s2 * 4 + quad) ^ (l15 & 7))) * 8]);
                    acc[u] = __builtin_amdgcn_mfma_f32_16x16x32_bf16(pa, vf, acc[u], 0, 0, 0);
                }
            }
        }

        #pragma unroll
        for (int r = 0; r < 4; ++r) {
            float inv = 1.0f / accl[r];
            int row = qrow0 + quad * 4 + r;
            __bf16* op = ao + (size_t)(b * 1024 + row) * 4096 + (h * 4 + i) * 128;
            #pragma unroll
            for (int u = 0; u < 8; ++u)
                op[u * 16 + l15] = (__bf16)(acc[u][r] * inv);
        }
    }
}

// ---------------------------------------------------------------------------
extern "C" void kernel_launch(void* const* d_in, const int* in_sizes, int n_in,
                              void* d_out, int out_size, void* d_ws, size_t ws_size,
                              hipStream_t stream)
{
    const float* x  = (const float*)d_in[0];   // [2048][2048]
    const float* Wq = (const float*)d_in[1];   // [2048][4096]
    const float* Wk = (const float*)d_in[2];   // [2048][1024]
    const float* Wv = (const float*)d_in[3];   // [2048][1024]
    const float* Wo = (const float*)d_in[4];   // [4096][2048]
    float* out = (float*)d_out;                // [2048][2048]

    const size_t MB = 1024 * 1024;
    char* ws = (char*)d_ws;
    __bf16* qkv  = (__bf16*)(ws);              // [2048][6144]    0-24 MB
    __bf16* vtb  = (__bf16*)(ws + 24 * MB);    // [16][128][1024] 24-28 MB
    __bf16* xb   = (__bf16*)(ws + 28 * MB);    // [2048][2048]    28-36 MB
    __bf16* Wt   = (__bf16*)(ws + 36 * MB);    // [6144][2048]    36-60 MB (dead after GEMM1)
    __bf16* ao   = (__bf16*)(ws + 28 * MB);    // [2048][4096]    28-44 MB (after GEMM1)
    __bf16* WoT  = (__bf16*)(ws + 44 * MB);    // [2048][4096]    44-60 MB (after GEMM1)
    __bf16* part = (__bf16*)(ws);              // [2][2048][2048] 0-16 MB (after attn; qkv dead)

    // 1) prep: convert x + transpose Wq/Wk/Wv (14336 blocks)
    prep_kernel<<<14336, 256, 0, stream>>>(x, xb, Wq, Wk, Wv, Wt);
    // 2) fused QKV projection: qkv[2048][6144]
    gemm_bt<__bf16><<<dim3(48, 16), 256, 0, stream>>>(xb, Wt, qkv, 2048, 6144, 2048, 2048, 2048, 6144);
    // 3) Wo transpose (WoT overlaps Wt -> must follow GEMM1)
    transpose_cvt_kernel<<<dim3(64, 128), dim3(32, 8), 0, stream>>>(Wo, WoT, 4096, 2048);
    // 4) RoPE + V transpose
    rope_vtrans_kernel<<<4608, 256, 0, stream>>>(qkv, vtb);
    // 5) attention (writes ao; qkv dead afterwards)
    attn_kernel<<<dim3(16, 16), 512, 0, stream>>>(qkv, vtb, ao);
    // 6) output projection, split-K=2, bf16 partials into dead qkv region
    gemm_bt<__bf16><<<dim3(16, 16, 2), 256, 0, stream>>>(ao, WoT, part, 2048, 2048, 2048, 4096, 4096, 2048);
    // 7) reduce partials -> fp32 out
    reduce_kernel<<<2048, 256, 0, stream>>>(part, out);
}

// Round 7
// 300.327 us; speedup vs baseline: 2.9504x; 1.0773x over previous
//
#include <hip/hip_runtime.h>
#include <hip/hip_bf16.h>

typedef __bf16 bf16x8 __attribute__((ext_vector_type(8)));
typedef float floatx4 __attribute__((ext_vector_type(4)));

// async global->LDS, 16B per lane; LDS dst = wave-uniform base + lane*16
static __device__ __forceinline__ void async_cp16(const __bf16* g, __bf16* l) {
    typedef const __attribute__((address_space(1))) unsigned int gu32;
    typedef __attribute__((address_space(3))) unsigned int lu32;
    __builtin_amdgcn_global_load_lds((gu32*)g, (lu32*)l, 16, 0, 0);
}

// ---------------------------------------------------------------------------
// Fused prep: blocks [0,8192) transpose Wq; [8192,10240) Wk; [10240,12288) Wv;
// [12288,14336) convert x -> bf16.
// ---------------------------------------------------------------------------
__global__ __launch_bounds__(256) void prep_kernel(
    const float* __restrict__ x,  __bf16* __restrict__ xb,
    const float* __restrict__ Wq, const float* __restrict__ Wk,
    const float* __restrict__ Wv, __bf16* __restrict__ Wt)
{
    __shared__ float tile[32][33];
    const int bk  = blockIdx.x;
    const int tid = threadIdx.x;
    const int tx  = tid & 31, ty = tid >> 5;

    if (bk < 12288) {
        const float* src; __bf16* dst; int R = 2048, C; int bxx, byy;
        if (bk < 8192)        { src = Wq; dst = Wt;                          C = 4096; bxx = bk & 127;           byy = bk >> 7; }
        else if (bk < 10240)  { src = Wk; dst = Wt + (size_t)4096 * 2048;    C = 1024; bxx = (bk - 8192) & 31;   byy = (bk - 8192) >> 5; }
        else                  { src = Wv; dst = Wt + (size_t)5120 * 2048;    C = 1024; bxx = (bk - 10240) & 31;  byy = (bk - 10240) >> 5; }
        const int c0 = bxx * 32, r0 = byy * 32;
        #pragma unroll
        for (int j = 0; j < 4; ++j)
            tile[ty * 4 + j][tx] = src[(size_t)(r0 + ty * 4 + j) * C + c0 + tx];
        __syncthreads();
        #pragma unroll
        for (int j = 0; j < 4; ++j)
            dst[(size_t)(c0 + ty * 4 + j) * R + r0 + tx] = (__bf16)tile[tx][ty * 4 + j];
    } else {
        int idx = (bk - 12288) * 256 + tid;
        const float* p = x + (size_t)idx * 8;
        float4 f0 = *(const float4*)p;
        float4 f1 = *(const float4*)(p + 4);
        union { uint4 u; __bf16 b[8]; } o;
        o.b[0] = (__bf16)f0.x; o.b[1] = (__bf16)f0.y; o.b[2] = (__bf16)f0.z; o.b[3] = (__bf16)f0.w;
        o.b[4] = (__bf16)f1.x; o.b[5] = (__bf16)f1.y; o.b[6] = (__bf16)f1.z; o.b[7] = (__bf16)f1.w;
        *(uint4*)(xb + (size_t)idx * 8) = o.u;
    }
}

// ---------------------------------------------------------------------------
// Fused RoPE + V-transpose + Wo-transpose (all post-GEMM1, independent).
// Blocks [0,2560): rope; [2560,4608): vtrans; [4608,12800): Wo transpose.
// ---------------------------------------------------------------------------
__global__ __launch_bounds__(256) void rope_vtrans_wot_kernel(
    __bf16* __restrict__ qkv, __bf16* __restrict__ vt,
    const float* __restrict__ Wo, __bf16* __restrict__ WoT)
{
    __shared__ float tilef[32][33];
    __shared__ __bf16 tileb[32][33];
    const int bk  = blockIdx.x;
    const int tid = threadIdx.x;

    if (bk < 2560) {
        int idx  = bk * 256 + tid;
        int part = idx & 7;
        int t    = idx >> 3;
        int head = t % 40;
        int row  = t / 40;
        int n    = row & 1023;
        int col0 = (head < 32) ? head * 128 : 4096 + (head - 32) * 128;
        size_t base = (size_t)row * 6144 + col0 + part * 8;

        union { uint4 u; __bf16 b[8]; } x1, x2, o1, o2;
        x1.u = *(const uint4*)(qkv + base);
        x2.u = *(const uint4*)(qkv + base + 64);
        #pragma unroll
        for (int e = 0; e < 8; ++e) {
            int j = part * 8 + e;
            float inv_freq = exp2f(-(float)j * 0.20762050593046015f); // log2(1e4)/64
            float ang = (float)n * inv_freq;
            float sv, cv;
            __sincosf(ang, &sv, &cv);
            float a = (float)x1.b[e], b2 = (float)x2.b[e];
            o1.b[e] = (__bf16)(a * cv - b2 * sv);
            o2.b[e] = (__bf16)(a * sv + b2 * cv);
        }
        *(uint4*)(qkv + base)      = o1.u;
        *(uint4*)(qkv + base + 64) = o2.u;
    } else if (bk < 4608) {
        int idx = bk - 2560;
        const int tx = tid & 31, ty = tid >> 5;
        const int k0 = (idx & 31) * 32;
        const int v0 = ((idx >> 5) & 3) * 32;
        const int bh = idx >> 7;
        const int b = bh >> 3, h = bh & 7;
        #pragma unroll
        for (int j = 0; j < 4; ++j)
            tileb[ty * 4 + j][tx] =
                qkv[(size_t)(b * 1024 + k0 + ty * 4 + j) * 6144 + 5120 + h * 128 + v0 + tx];
        __syncthreads();
        #pragma unroll
        for (int j = 0; j < 4; ++j)
            vt[((size_t)bh * 128 + v0 + ty * 4 + j) * 1024 + k0 + tx] = tileb[tx][ty * 4 + j];
    } else {
        int idx = bk - 4608;                 // Wo [4096][2048] -> WoT [2048][4096]
        const int tx = tid & 31, ty = tid >> 5;
        const int c0 = (idx & 63) * 32;      // 2048/32 = 64
        const int r0 = (idx >> 6) * 32;      // 4096/32 = 128
        #pragma unroll
        for (int j = 0; j < 4; ++j)
            tilef[ty * 4 + j][tx] = Wo[(size_t)(r0 + ty * 4 + j) * 2048 + c0 + tx];
        __syncthreads();
        #pragma unroll
        for (int j = 0; j < 4; ++j)
            WoT[(size_t)(c0 + ty * 4 + j) * 4096 + r0 + tx] = (__bf16)tilef[tx][ty * 4 + j];
    }
}

// ---------------------------------------------------------------------------
// GEMM: C[z][M][N] = A[M][koff:] * Bt[N][koff:]^T, bf16, tile 128x128, BK=64.
// XOR-swizzled LDS (chunk slot c of row r holds global chunk c^(r&7)), DMA
// staging. Split-K: koff = z*kc_base, Kc = kc_base (+kc_extra for last z).
// ---------------------------------------------------------------------------
__global__ __launch_bounds__(256) void gemm_bt(
    const __bf16* __restrict__ A,
    const __bf16* __restrict__ Bt,
    __bf16* __restrict__ C,
    int M, int lda, int ldb, int ldc,
    int kc_base, int kc_extra)
{
    __shared__ __bf16 As[128 * 64];
    __shared__ __bf16 Bs[128 * 64];

    const int tid  = threadIdx.x;
    const int wave = tid >> 6;
    const int lane = tid & 63;
    const int quad = lane >> 4;
    const int l15  = lane & 15;
    const int wr   = wave >> 1, wc = wave & 1;

    const int bm = blockIdx.y * 128;
    const int bn = blockIdx.x * 128;
    const int z  = blockIdx.z;
    const int Kc = kc_base + ((z == (int)gridDim.z - 1) ? kc_extra : 0);

    A  += (size_t)z * kc_base;
    Bt += (size_t)z * kc_base;
    C  += (size_t)z * M * ldc;

    floatx4 acc[16];
    #pragma unroll
    for (int i = 0; i < 16; ++i) acc[i] = floatx4{0.f, 0.f, 0.f, 0.f};

    // staging: wave w stages rows w*32+{0..31}; per instr 8 rows x 8 chunks
    const int sr = lane >> 3;                 // row within 8
    const int sc = ((lane & 7) ^ sr) * 8;     // swizzled chunk (elems)
    const __bf16* a0 = A  + (size_t)(bm + wave * 32 + sr) * lda + sc;
    const __bf16* b0 = Bt + (size_t)(bn + wave * 32 + sr) * ldb + sc;
    __bf16* asd = As + (wave * 32) * 64;
    __bf16* bsd = Bs + (wave * 32) * 64;

    for (int k0 = 0; k0 < Kc; k0 += 64) {
        __syncthreads();
        #pragma unroll
        for (int r = 0; r < 4; ++r) {
            async_cp16(a0 + (size_t)(r * 8) * lda + k0, asd + (r * 8) * 64);
            async_cp16(b0 + (size_t)(r * 8) * ldb + k0, bsd + (r * 8) * 64);
        }
        __syncthreads();

        #pragma unroll
        for (int ko = 0; ko < 2; ++ko) {
            bf16x8 af[4], bf[4];
            #pragma unroll
            for (int t = 0; t < 4; ++t)
                af[t] = *(const bf16x8*)(
                    &As[(wr * 64 + t * 16 + l15) * 64 + (((ko * 4 + quad) ^ (l15 & 7)) * 8)]);
            #pragma unroll
            for (int u = 0; u < 4; ++u)
                bf[u] = *(const bf16x8*)(
                    &Bs[(wc * 64 + u * 16 + l15) * 64 + (((ko * 4 + quad) ^ (l15 & 7)) * 8)]);
            #pragma unroll
            for (int t = 0; t < 4; ++t)
                #pragma unroll
                for (int u = 0; u < 4; ++u)
                    acc[t * 4 + u] = __builtin_amdgcn_mfma_f32_16x16x32_bf16(
                        af[t], bf[u], acc[t * 4 + u], 0, 0, 0);
        }
    }

    #pragma unroll
    for (int t = 0; t < 4; ++t)
        #pragma unroll
        for (int u = 0; u < 4; ++u)
            #pragma unroll
            for (int r = 0; r < 4; ++r) {
                int row = bm + wr * 64 + t * 16 + quad * 4 + r;
                int col = bn + wc * 64 + u * 16 + l15;
                C[(size_t)row * ldc + col] = (__bf16)acc[t * 4 + u][r];
            }
}

// ---------------------------------------------------------------------------
// Split-K reduce: out = sum of 3 bf16 partials, fp32 out.
// ---------------------------------------------------------------------------
__global__ __launch_bounds__(256) void reduce_kernel(
    const __bf16* __restrict__ part, float* __restrict__ out)
{
    int idx = blockIdx.x * 256 + threadIdx.x;      // 8 elems each
    const size_t S = (size_t)2048 * 2048;
    union { uint4 u; __bf16 b[8]; } p0, p1, p2;
    p0.u = *(const uint4*)(part + (size_t)idx * 8);
    p1.u = *(const uint4*)(part + S + (size_t)idx * 8);
    p2.u = *(const uint4*)(part + 2 * S + (size_t)idx * 8);
    float4 o0, o1;
    o0.x = (float)p0.b[0] + (float)p1.b[0] + (float)p2.b[0];
    o0.y = (float)p0.b[1] + (float)p1.b[1] + (float)p2.b[1];
    o0.z = (float)p0.b[2] + (float)p1.b[2] + (float)p2.b[2];
    o0.w = (float)p0.b[3] + (float)p1.b[3] + (float)p2.b[3];
    o1.x = (float)p0.b[4] + (float)p1.b[4] + (float)p2.b[4];
    o1.y = (float)p0.b[5] + (float)p1.b[5] + (float)p2.b[5];
    o1.z = (float)p0.b[6] + (float)p1.b[6] + (float)p2.b[6];
    o1.w = (float)p0.b[7] + (float)p1.b[7] + (float)p2.b[7];
    *(float4*)(out + (size_t)idx * 8)     = o0;
    *(float4*)(out + (size_t)idx * 8 + 4) = o1;
}

// ---------------------------------------------------------------------------
// Causal flash attention (R5 structure: balanced pairing, max-free softmax,
// swizzled DMA staging).
// ---------------------------------------------------------------------------
__global__ __launch_bounds__(512, 2) void attn_kernel(
    const __bf16* __restrict__ qkv,
    const __bf16* __restrict__ vt,
    __bf16* __restrict__ ao)
{
    const int PS_LD = 72;
    __shared__ __bf16 Ks[64 * 128];      // [key][kdim], swizzled
    __shared__ __bf16 Vs[128 * 64];      // [vdim][key], swizzled
    __shared__ __bf16 Ps[8][16 * PS_LD]; // per-wave [qrow][key], padded

    const int tid  = threadIdx.x;
    const int wave = tid >> 6;
    const int lane = tid & 63;
    const int quad = lane >> 4;
    const int l15  = lane & 15;
    const int i    = wave >> 1;
    const int rt   = wave & 1;

    const int pair = blockIdx.x;
    const int bh   = blockIdx.y;
    const int b    = bh >> 3, h = bh & 7;
    const __bf16* vtb = vt + (size_t)bh * 128 * 1024;

    const int keyA = wave * 8 + (lane >> 4);
    const int keyB = keyA + 4;
    const int chA  = (lane & 15) ^ (keyA & 15);
    const int chB  = (lane & 15) ^ (keyB & 15);
    const __bf16* gK0 = qkv + (size_t)(b * 1024 + keyA) * 6144 + 4096 + h * 128 + chA * 8;
    const __bf16* gK1 = qkv + (size_t)(b * 1024 + keyB) * 6144 + 4096 + h * 128 + chB * 8;
    __bf16* lK0 = Ks + (wave * 8) * 128;
    __bf16* lK1 = Ks + (wave * 8 + 4) * 128;

    const int vdA = wave * 16 + (lane >> 3);
    const int vdB = vdA + 8;
    const int cvA = (lane & 7) ^ (vdA & 7);
    const int cvB = (lane & 7) ^ (vdB & 7);
    const __bf16* gV0 = vtb + (size_t)vdA * 1024 + cvA * 8;
    const __bf16* gV1 = vtb + (size_t)vdB * 1024 + cvB * 8;
    __bf16* lV0 = Vs + (wave * 16) * 64;
    __bf16* lV1 = Vs + (wave * 16 + 8) * 64;

    bf16x8 onesf;
    #pragma unroll
    for (int j = 0; j < 8; ++j) onesf[j] = (__bf16)1.0f;

    const float C2 = 0.12751898549f;   // (1/sqrt(128)) * log2(e)

    #pragma unroll
    for (int ph = 0; ph < 2; ++ph) {
        const int qt    = ph ? (31 - pair) : pair;
        const int qrow0 = qt * 32 + rt * 16;

        const __bf16* qp = qkv + (size_t)(b * 1024 + qrow0 + l15) * 6144 + (h * 4 + i) * 128;
        bf16x8 qf[4];
        #pragma unroll
        for (int c = 0; c < 4; ++c)
            qf[c] = *(const bf16x8*)(qp + c * 32 + quad * 8);

        floatx4 acc[8];
        #pragma unroll
        for (int u = 0; u < 8; ++u) acc[u] = floatx4{0.f, 0.f, 0.f, 0.f};
        floatx4 accl = floatx4{0.f, 0.f, 0.f, 0.f};

        const int ntiles = (qt >> 1) + 1;
        for (int t = 0; t < ntiles; ++t) {
            const int kt = t * 64;
            __syncthreads();
            async_cp16(gK0 + (size_t)kt * 6144, lK0);
            async_cp16(gK1 + (size_t)kt * 6144, lK1);
            async_cp16(gV0 + kt, lV0);
            async_cp16(gV1 + kt, lV1);
            __syncthreads();

            floatx4 s[4];
            #pragma unroll
            for (int ks = 0; ks < 4; ++ks) s[ks] = floatx4{0.f, 0.f, 0.f, 0.f};
            #pragma unroll
            for (int c = 0; c < 4; ++c) {
                #pragma unroll
                for (int ks = 0; ks < 4; ++ks) {
                    bf16x8 kf = *(const bf16x8*)(
                        &Ks[(ks * 16 + l15) * 128 + ((c * 4 + quad) ^ l15) * 8]);
                    s[ks] = __builtin_amdgcn_mfma_f32_16x16x32_bf16(qf[c], kf, s[ks], 0, 0, 0);
                }
            }

            #pragma unroll
            for (int r = 0; r < 4; ++r) {
                int qrow = qrow0 + quad * 4 + r;
                #pragma unroll
                for (int ks = 0; ks < 4; ++ks) {
                    int kc = kt + ks * 16 + l15;
                    float p = (kc <= qrow) ? exp2f(s[ks][r] * C2) : 0.0f;
                    Ps[wave][(quad * 4 + r) * PS_LD + ks * 16 + l15] = (__bf16)p;
                }
            }

            #pragma unroll
            for (int s2 = 0; s2 < 2; ++s2) {
                bf16x8 pa = *(const bf16x8*)(&Ps[wave][l15 * PS_LD + s2 * 32 + quad * 8]);
                accl = __builtin_amdgcn_mfma_f32_16x16x32_bf16(pa, onesf, accl, 0, 0, 0);
                #pragma unroll
                for (int u = 0; u < 8; ++u) {
                    bf16x8 vf = *(const bf16x8*)(
                        &Vs[(u * 16 + l15) * 64 + (((s2 * 4 + quad) ^ (l15 & 7))) * 8]);
                    acc[u] = __builtin_amdgcn_mfma_f32_16x16x32_bf16(pa, vf, acc[u], 0, 0, 0);
                }
            }
        }

        #pragma unroll
        for (int r = 0; r < 4; ++r) {
            float inv = 1.0f / accl[r];
            int row = qrow0 + quad * 4 + r;
            __bf16* op = ao + (size_t)(b * 1024 + row) * 4096 + (h * 4 + i) * 128;
            #pragma unroll
            for (int u = 0; u < 8; ++u)
                op[u * 16 + l15] = (__bf16)(acc[u][r] * inv);
        }
    }
}

// ---------------------------------------------------------------------------
extern "C" void kernel_launch(void* const* d_in, const int* in_sizes, int n_in,
                              void* d_out, int out_size, void* d_ws, size_t ws_size,
                              hipStream_t stream)
{
    const float* x  = (const float*)d_in[0];   // [2048][2048]
    const float* Wq = (const float*)d_in[1];   // [2048][4096]
    const float* Wk = (const float*)d_in[2];   // [2048][1024]
    const float* Wv = (const float*)d_in[3];   // [2048][1024]
    const float* Wo = (const float*)d_in[4];   // [4096][2048]
    float* out = (float*)d_out;                // [2048][2048]

    const size_t MB = 1024 * 1024;
    char* ws = (char*)d_ws;                    // 60 MB total
    __bf16* qkv  = (__bf16*)(ws);              // [2048][6144]    0-24  (dead after attn)
    __bf16* vtb  = (__bf16*)(ws + 24 * MB);    // [16][128][1024] 24-28 (dead after attn)
    __bf16* xb   = (__bf16*)(ws + 28 * MB);    // [2048][2048]    28-36 (dead after GEMM1)
    __bf16* Wt   = (__bf16*)(ws + 36 * MB);    // [6144][2048]    36-60 (dead after GEMM1)
    __bf16* WoT  = (__bf16*)(ws + 28 * MB);    // [2048][4096]    28-44 (post-GEMM1)
    __bf16* ao   = (__bf16*)(ws + 44 * MB);    // [2048][4096]    44-60 (post-GEMM1)
    __bf16* part = (__bf16*)(ws);              // [3][2048][2048] 0-24  (post-attn)

    // 1) prep: convert x + transpose Wq/Wk/Wv
    prep_kernel<<<14336, 256, 0, stream>>>(x, xb, Wq, Wk, Wv, Wt);
    // 2) fused QKV projection: qkv[2048][6144]
    gemm_bt<<<dim3(48, 16), 256, 0, stream>>>(xb, Wt, qkv, 2048, 2048, 2048, 6144, 2048, 0);
    // 3) RoPE + V transpose + Wo transpose (WoT overwrites xb/Wt head)
    rope_vtrans_wot_kernel<<<12800, 256, 0, stream>>>(qkv, vtb, Wo, WoT);
    // 4) attention (writes ao; qkv/vtb dead afterwards)
    attn_kernel<<<dim3(16, 16), 512, 0, stream>>>(qkv, vtb, ao);
    // 5) output projection, split-K=3 (1344/1344/1408), partials in dead qkv
    gemm_bt<<<dim3(16, 16, 3), 256, 0, stream>>>(ao, WoT, part, 2048, 4096, 4096, 2048, 1344, 64);
    // 6) reduce partials -> fp32 out
    reduce_kernel<<<2048, 256, 0, stream>>>(part, out);
}

// Round 8
// 296.694 us; speedup vs baseline: 2.9865x; 1.0122x over previous
//
#include <hip/hip_runtime.h>
#include <hip/hip_bf16.h>

typedef __bf16 bf16x8 __attribute__((ext_vector_type(8)));
typedef float floatx4 __attribute__((ext_vector_type(4)));

// async global->LDS, 16B per lane; LDS dst = wave-uniform base + lane*16
static __device__ __forceinline__ void async_cp16(const __bf16* g, __bf16* l) {
    typedef const __attribute__((address_space(1))) unsigned int gu32;
    typedef __attribute__((address_space(3))) unsigned int lu32;
    __builtin_amdgcn_global_load_lds((gu32*)g, (lu32*)l, 16, 0, 0);
}

// ---------------------------------------------------------------------------
// 64x64 transpose tile, fp32 src -> bf16 dst. Vectorized global I/O both sides.
// src[R][C], dst[C][R]; tile origin (r0, c0).
// ---------------------------------------------------------------------------
static __device__ __forceinline__ void tile64_f32(
    const float* __restrict__ src, __bf16* __restrict__ dst,
    int R, int C, int r0, int c0, int tid, __bf16* t /* [64*72] */)
{
    {
        const int r = tid >> 2, cq = (tid & 3) * 16;
        const float* p = src + (size_t)(r0 + r) * C + c0 + cq;
        float4 f0 = *(const float4*)(p);
        float4 f1 = *(const float4*)(p + 4);
        float4 f2 = *(const float4*)(p + 8);
        float4 f3 = *(const float4*)(p + 12);
        __bf16 v[16] = {
            (__bf16)f0.x, (__bf16)f0.y, (__bf16)f0.z, (__bf16)f0.w,
            (__bf16)f1.x, (__bf16)f1.y, (__bf16)f1.z, (__bf16)f1.w,
            (__bf16)f2.x, (__bf16)f2.y, (__bf16)f2.z, (__bf16)f2.w,
            (__bf16)f3.x, (__bf16)f3.y, (__bf16)f3.z, (__bf16)f3.w };
        #pragma unroll
        for (int e = 0; e < 16; ++e) t[(cq + e) * 72 + r] = v[e];
    }
    __syncthreads();
    {
        const int c = tid >> 2, rq = (tid & 3) * 16;
        uint4 u0 = *(const uint4*)(&t[c * 72 + rq]);
        uint4 u1 = *(const uint4*)(&t[c * 72 + rq + 8]);
        __bf16* q = dst + (size_t)(c0 + c) * R + r0 + rq;
        *(uint4*)(q)     = u0;
        *(uint4*)(q + 8) = u1;
    }
}

// same, bf16 src -> bf16 dst (for V transpose); src stride lds_src, dst stride R
static __device__ __forceinline__ void tile64_b16(
    const __bf16* __restrict__ src, __bf16* __restrict__ dst,
    int src_ld, int dst_ld, int tid, __bf16* t /* [64*72] */)
{
    {
        const int r = tid >> 2, cq = (tid & 3) * 16;
        const __bf16* p = src + (size_t)r * src_ld + cq;
        union { uint4 u; __bf16 b[8]; } a0, a1;
        a0.u = *(const uint4*)(p);
        a1.u = *(const uint4*)(p + 8);
        #pragma unroll
        for (int e = 0; e < 8; ++e) {
            t[(cq + e) * 72 + r]     = a0.b[e];
            t[(cq + 8 + e) * 72 + r] = a1.b[e];
        }
    }
    __syncthreads();
    {
        const int c = tid >> 2, rq = (tid & 3) * 16;
        uint4 u0 = *(const uint4*)(&t[c * 72 + rq]);
        uint4 u1 = *(const uint4*)(&t[c * 72 + rq + 8]);
        __bf16* q = dst + (size_t)c * dst_ld + rq;
        *(uint4*)(q)     = u0;
        *(uint4*)(q + 8) = u1;
    }
}

// ---------------------------------------------------------------------------
// Fused prep: [0,2048) Wq-T; [2048,2560) Wk-T; [2560,3072) Wv-T;
// [3072,5120) x convert. 256 threads.
// ---------------------------------------------------------------------------
__global__ __launch_bounds__(256) void prep_kernel(
    const float* __restrict__ x,  __bf16* __restrict__ xb,
    const float* __restrict__ Wq, const float* __restrict__ Wk,
    const float* __restrict__ Wv, __bf16* __restrict__ Wt)
{
    __shared__ __bf16 t[64 * 72];
    const int bk  = blockIdx.x;
    const int tid = threadIdx.x;

    if (bk < 2048) {            // Wq [2048][4096] -> Wt[0..4096) rows
        int ct = bk & 63, rt = bk >> 6;
        tile64_f32(Wq, Wt, 2048, 4096, rt * 64, ct * 64, tid, t);
    } else if (bk < 2560) {     // Wk [2048][1024] -> Wt[4096..5120)
        int idx = bk - 2048, ct = idx & 15, rt = idx >> 4;
        tile64_f32(Wk, Wt + (size_t)4096 * 2048, 2048, 1024, rt * 64, ct * 64, tid, t);
    } else if (bk < 3072) {     // Wv [2048][1024] -> Wt[5120..6144)
        int idx = bk - 2560, ct = idx & 15, rt = idx >> 4;
        tile64_f32(Wv, Wt + (size_t)5120 * 2048, 2048, 1024, rt * 64, ct * 64, tid, t);
    } else {                    // x convert
        int idx = (bk - 3072) * 256 + tid;
        const float* p = x + (size_t)idx * 8;
        float4 f0 = *(const float4*)p;
        float4 f1 = *(const float4*)(p + 4);
        union { uint4 u; __bf16 b[8]; } o;
        o.b[0] = (__bf16)f0.x; o.b[1] = (__bf16)f0.y; o.b[2] = (__bf16)f0.z; o.b[3] = (__bf16)f0.w;
        o.b[4] = (__bf16)f1.x; o.b[5] = (__bf16)f1.y; o.b[6] = (__bf16)f1.z; o.b[7] = (__bf16)f1.w;
        *(uint4*)(xb + (size_t)idx * 8) = o.u;
    }
}

// ---------------------------------------------------------------------------
// Fused RoPE + V-transpose + Wo-transpose (post-GEMM1).
// [0,2560): rope; [2560,3072): vtrans; [3072,5120): Wo-T.
// ---------------------------------------------------------------------------
__global__ __launch_bounds__(256) void rope_vtrans_wot_kernel(
    __bf16* __restrict__ qkv, __bf16* __restrict__ vt,
    const float* __restrict__ Wo, __bf16* __restrict__ WoT)
{
    __shared__ __bf16 t[64 * 72];
    const int bk  = blockIdx.x;
    const int tid = threadIdx.x;

    if (bk < 2560) {
        int idx  = bk * 256 + tid;
        int part = idx & 7;
        int tt   = idx >> 3;
        int head = tt % 40;
        int row  = tt / 40;
        int n    = row & 1023;
        int col0 = (head < 32) ? head * 128 : 4096 + (head - 32) * 128;
        size_t base = (size_t)row * 6144 + col0 + part * 8;

        union { uint4 u; __bf16 b[8]; } x1, x2, o1, o2;
        x1.u = *(const uint4*)(qkv + base);
        x2.u = *(const uint4*)(qkv + base + 64);
        #pragma unroll
        for (int e = 0; e < 8; ++e) {
            int j = part * 8 + e;
            float inv_freq = exp2f(-(float)j * 0.20762050593046015f); // log2(1e4)/64
            float ang = (float)n * inv_freq;
            float sv, cv;
            __sincosf(ang, &sv, &cv);
            float a = (float)x1.b[e], b2 = (float)x2.b[e];
            o1.b[e] = (__bf16)(a * cv - b2 * sv);
            o2.b[e] = (__bf16)(a * sv + b2 * cv);
        }
        *(uint4*)(qkv + base)      = o1.u;
        *(uint4*)(qkv + base + 64) = o2.u;
    } else if (bk < 3072) {      // V cols of qkv -> vt[bh][128][1024]
        int idx = bk - 2560;     // 512: bh = idx>>5, rem 32 = 16 ktiles x 2 vtiles
        int bh = idx >> 5, rem = idx & 31;
        int k0 = (rem >> 1) * 64, v0 = (rem & 1) * 64;
        int b = bh >> 3, h = bh & 7;
        const __bf16* src = qkv + (size_t)(b * 1024 + k0) * 6144 + 5120 + h * 128 + v0;
        __bf16* dst = vt + ((size_t)bh * 128 + v0) * 1024 + k0;
        tile64_b16(src, dst, 6144, 1024, tid, t);
    } else {                     // Wo [4096][2048] -> WoT [2048][4096]
        int idx = bk - 3072;     // 2048: 32 ctiles x 64 rtiles
        int ct = idx & 31, rt = idx >> 5;
        tile64_f32(Wo, WoT, 4096, 2048, rt * 64, ct * 64, tid, t);
    }
}

// ---------------------------------------------------------------------------
// GEMM: C[z][M][N] = A[M][koff:] * Bt[N][koff:]^T, bf16, tile 128x128, BK=64.
// XOR-swizzled LDS, DMA staging. Split-K: koff = z*kc_base.
// ---------------------------------------------------------------------------
__global__ __launch_bounds__(256) void gemm_bt(
    const __bf16* __restrict__ A,
    const __bf16* __restrict__ Bt,
    __bf16* __restrict__ C,
    int M, int lda, int ldb, int ldc,
    int kc_base, int kc_extra)
{
    __shared__ __bf16 As[128 * 64];
    __shared__ __bf16 Bs[128 * 64];

    const int tid  = threadIdx.x;
    const int wave = tid >> 6;
    const int lane = tid & 63;
    const int quad = lane >> 4;
    const int l15  = lane & 15;
    const int wr   = wave >> 1, wc = wave & 1;

    const int bm = blockIdx.y * 128;
    const int bn = blockIdx.x * 128;
    const int z  = blockIdx.z;
    const int Kc = kc_base + ((z == (int)gridDim.z - 1) ? kc_extra : 0);

    A  += (size_t)z * kc_base;
    Bt += (size_t)z * kc_base;
    C  += (size_t)z * M * ldc;

    floatx4 acc[16];
    #pragma unroll
    for (int i = 0; i < 16; ++i) acc[i] = floatx4{0.f, 0.f, 0.f, 0.f};

    const int sr = lane >> 3;
    const int sc = ((lane & 7) ^ sr) * 8;
    const __bf16* a0 = A  + (size_t)(bm + wave * 32 + sr) * lda + sc;
    const __bf16* b0 = Bt + (size_t)(bn + wave * 32 + sr) * ldb + sc;
    __bf16* asd = As + (wave * 32) * 64;
    __bf16* bsd = Bs + (wave * 32) * 64;

    for (int k0 = 0; k0 < Kc; k0 += 64) {
        __syncthreads();
        #pragma unroll
        for (int r = 0; r < 4; ++r) {
            async_cp16(a0 + (size_t)(r * 8) * lda + k0, asd + (r * 8) * 64);
            async_cp16(b0 + (size_t)(r * 8) * ldb + k0, bsd + (r * 8) * 64);
        }
        __syncthreads();

        #pragma unroll
        for (int ko = 0; ko < 2; ++ko) {
            bf16x8 af[4], bf[4];
            #pragma unroll
            for (int t = 0; t < 4; ++t)
                af[t] = *(const bf16x8*)(
                    &As[(wr * 64 + t * 16 + l15) * 64 + (((ko * 4 + quad) ^ (l15 & 7)) * 8)]);
            #pragma unroll
            for (int u = 0; u < 4; ++u)
                bf[u] = *(const bf16x8*)(
                    &Bs[(wc * 64 + u * 16 + l15) * 64 + (((ko * 4 + quad) ^ (l15 & 7)) * 8)]);
            #pragma unroll
            for (int t = 0; t < 4; ++t)
                #pragma unroll
                for (int u = 0; u < 4; ++u)
                    acc[t * 4 + u] = __builtin_amdgcn_mfma_f32_16x16x32_bf16(
                        af[t], bf[u], acc[t * 4 + u], 0, 0, 0);
        }
    }

    #pragma unroll
    for (int t = 0; t < 4; ++t)
        #pragma unroll
        for (int u = 0; u < 4; ++u)
            #pragma unroll
            for (int r = 0; r < 4; ++r) {
                int row = bm + wr * 64 + t * 16 + quad * 4 + r;
                int col = bn + wc * 64 + u * 16 + l15;
                C[(size_t)row * ldc + col] = (__bf16)acc[t * 4 + u][r];
            }
}

// ---------------------------------------------------------------------------
// Split-K reduce: out = sum of 3 bf16 partials, fp32 out.
// ---------------------------------------------------------------------------
__global__ __launch_bounds__(256) void reduce_kernel(
    const __bf16* __restrict__ part, float* __restrict__ out)
{
    int idx = blockIdx.x * 256 + threadIdx.x;
    const size_t S = (size_t)2048 * 2048;
    union { uint4 u; __bf16 b[8]; } p0, p1, p2;
    p0.u = *(const uint4*)(part + (size_t)idx * 8);
    p1.u = *(const uint4*)(part + S + (size_t)idx * 8);
    p2.u = *(const uint4*)(part + 2 * S + (size_t)idx * 8);
    float4 o0, o1;
    o0.x = (float)p0.b[0] + (float)p1.b[0] + (float)p2.b[0];
    o0.y = (float)p0.b[1] + (float)p1.b[1] + (float)p2.b[1];
    o0.z = (float)p0.b[2] + (float)p1.b[2] + (float)p2.b[2];
    o0.w = (float)p0.b[3] + (float)p1.b[3] + (float)p2.b[3];
    o1.x = (float)p0.b[4] + (float)p1.b[4] + (float)p2.b[4];
    o1.y = (float)p0.b[5] + (float)p1.b[5] + (float)p2.b[5];
    o1.z = (float)p0.b[6] + (float)p1.b[6] + (float)p2.b[6];
    o1.w = (float)p0.b[7] + (float)p1.b[7] + (float)p2.b[7];
    *(float4*)(out + (size_t)idx * 8)     = o0;
    *(float4*)(out + (size_t)idx * 8 + 4) = o1;
}

// ---------------------------------------------------------------------------
// Causal flash attention (R5 structure: balanced pairing, max-free softmax,
// swizzled DMA staging).
// ---------------------------------------------------------------------------
__global__ __launch_bounds__(512, 2) void attn_kernel(
    const __bf16* __restrict__ qkv,
    const __bf16* __restrict__ vt,
    __bf16* __restrict__ ao)
{
    const int PS_LD = 72;
    __shared__ __bf16 Ks[64 * 128];      // [key][kdim], swizzled
    __shared__ __bf16 Vs[128 * 64];      // [vdim][key], swizzled
    __shared__ __bf16 Ps[8][16 * PS_LD]; // per-wave [qrow][key], padded

    const int tid  = threadIdx.x;
    const int wave = tid >> 6;
    const int lane = tid & 63;
    const int quad = lane >> 4;
    const int l15  = lane & 15;
    const int i    = wave >> 1;
    const int rt   = wave & 1;

    const int pair = blockIdx.x;
    const int bh   = blockIdx.y;
    const int b    = bh >> 3, h = bh & 7;
    const __bf16* vtb = vt + (size_t)bh * 128 * 1024;

    const int keyA = wave * 8 + (lane >> 4);
    const int keyB = keyA + 4;
    const int chA  = (lane & 15) ^ (keyA & 15);
    const int chB  = (lane & 15) ^ (keyB & 15);
    const __bf16* gK0 = qkv + (size_t)(b * 1024 + keyA) * 6144 + 4096 + h * 128 + chA * 8;
    const __bf16* gK1 = qkv + (size_t)(b * 1024 + keyB) * 6144 + 4096 + h * 128 + chB * 8;
    __bf16* lK0 = Ks + (wave * 8) * 128;
    __bf16* lK1 = Ks + (wave * 8 + 4) * 128;

    const int vdA = wave * 16 + (lane >> 3);
    const int vdB = vdA + 8;
    const int cvA = (lane & 7) ^ (vdA & 7);
    const int cvB = (lane & 7) ^ (vdB & 7);
    const __bf16* gV0 = vtb + (size_t)vdA * 1024 + cvA * 8;
    const __bf16* gV1 = vtb + (size_t)vdB * 1024 + cvB * 8;
    __bf16* lV0 = Vs + (wave * 16) * 64;
    __bf16* lV1 = Vs + (wave * 16 + 8) * 64;

    bf16x8 onesf;
    #pragma unroll
    for (int j = 0; j < 8; ++j) onesf[j] = (__bf16)1.0f;

    const float C2 = 0.12751898549f;   // (1/sqrt(128)) * log2(e)

    #pragma unroll
    for (int ph = 0; ph < 2; ++ph) {
        const int qt    = ph ? (31 - pair) : pair;
        const int qrow0 = qt * 32 + rt * 16;

        const __bf16* qp = qkv + (size_t)(b * 1024 + qrow0 + l15) * 6144 + (h * 4 + i) * 128;
        bf16x8 qf[4];
        #pragma unroll
        for (int c = 0; c < 4; ++c)
            qf[c] = *(const bf16x8*)(qp + c * 32 + quad * 8);

        floatx4 acc[8];
        #pragma unroll
        for (int u = 0; u < 8; ++u) acc[u] = floatx4{0.f, 0.f, 0.f, 0.f};
        floatx4 accl = floatx4{0.f, 0.f, 0.f, 0.f};

        const int ntiles = (qt >> 1) + 1;
        for (int t = 0; t < ntiles; ++t) {
            const int kt = t * 64;
            __syncthreads();
            async_cp16(gK0 + (size_t)kt * 6144, lK0);
            async_cp16(gK1 + (size_t)kt * 6144, lK1);
            async_cp16(gV0 + kt, lV0);
            async_cp16(gV1 + kt, lV1);
            __syncthreads();

            floatx4 s[4];
            #pragma unroll
            for (int ks = 0; ks < 4; ++ks) s[ks] = floatx4{0.f, 0.f, 0.f, 0.f};
            #pragma unroll
            for (int c = 0; c < 4; ++c) {
                #pragma unroll
                for (int ks = 0; ks < 4; ++ks) {
                    bf16x8 kf = *(const bf16x8*)(
                        &Ks[(ks * 16 + l15) * 128 + ((c * 4 + quad) ^ l15) * 8]);
                    s[ks] = __builtin_amdgcn_mfma_f32_16x16x32_bf16(qf[c], kf, s[ks], 0, 0, 0);
                }
            }

            #pragma unroll
            for (int r = 0; r < 4; ++r) {
                int qrow = qrow0 + quad * 4 + r;
                #pragma unroll
                for (int ks = 0; ks < 4; ++ks) {
                    int kc = kt + ks * 16 + l15;
                    float p = (kc <= qrow) ? exp2f(s[ks][r] * C2) : 0.0f;
                    Ps[wave][(quad * 4 + r) * PS_LD + ks * 16 + l15] = (__bf16)p;
                }
            }

            #pragma unroll
            for (int s2 = 0; s2 < 2; ++s2) {
                bf16x8 pa = *(const bf16x8*)(&Ps[wave][l15 * PS_LD + s2 * 32 + quad * 8]);
                accl = __builtin_amdgcn_mfma_f32_16x16x32_bf16(pa, onesf, accl, 0, 0, 0);
                #pragma unroll
                for (int u = 0; u < 8; ++u) {
                    bf16x8 vf = *(const bf16x8*)(
                        &Vs[(u * 16 + l15) * 64 + (((s2 * 4 + quad) ^ (l15 & 7))) * 8]);
                    acc[u] = __builtin_amdgcn_mfma_f32_16x16x32_bf16(pa, vf, acc[u], 0, 0, 0);
                }
            }
        }

        #pragma unroll
        for (int r = 0; r < 4; ++r) {
            float inv = 1.0f / accl[r];
            int row = qrow0 + quad * 4 + r;
            __bf16* op = ao + (size_t)(b * 1024 + row) * 4096 + (h * 4 + i) * 128;
            #pragma unroll
            for (int u = 0; u < 8; ++u)
                op[u * 16 + l15] = (__bf16)(acc[u][r] * inv);
        }
    }
}

// ---------------------------------------------------------------------------
extern "C" void kernel_launch(void* const* d_in, const int* in_sizes, int n_in,
                              void* d_out, int out_size, void* d_ws, size_t ws_size,
                              hipStream_t stream)
{
    const float* x  = (const float*)d_in[0];   // [2048][2048]
    const float* Wq = (const float*)d_in[1];   // [2048][4096]
    const float* Wk = (const float*)d_in[2];   // [2048][1024]
    const float* Wv = (const float*)d_in[3];   // [2048][1024]
    const float* Wo = (const float*)d_in[4];   // [4096][2048]
    float* out = (float*)d_out;                // [2048][2048]

    const size_t MB = 1024 * 1024;
    char* ws = (char*)d_ws;                    // 60 MB total
    __bf16* qkv  = (__bf16*)(ws);              // [2048][6144]    0-24  (dead after attn)
    __bf16* vtb  = (__bf16*)(ws + 24 * MB);    // [16][128][1024] 24-28 (dead after attn)
    __bf16* xb   = (__bf16*)(ws + 28 * MB);    // [2048][2048]    28-36 (dead after GEMM1)
    __bf16* Wt   = (__bf16*)(ws + 36 * MB);    // [6144][2048]    36-60 (dead after GEMM1)
    __bf16* WoT  = (__bf16*)(ws + 28 * MB);    // [2048][4096]    28-44 (post-GEMM1)
    __bf16* ao   = (__bf16*)(ws + 44 * MB);    // [2048][4096]    44-60 (post-GEMM1)
    __bf16* part = (__bf16*)(ws);              // [3][2048][2048] 0-24  (post-attn)

    // 1) prep: transpose Wq/Wk/Wv (vectorized 64x64 tiles) + convert x
    prep_kernel<<<5120, 256, 0, stream>>>(x, xb, Wq, Wk, Wv, Wt);
    // 2) fused QKV projection: qkv[2048][6144]
    gemm_bt<<<dim3(48, 16), 256, 0, stream>>>(xb, Wt, qkv, 2048, 2048, 2048, 6144, 2048, 0);
    // 3) RoPE + V transpose + Wo transpose (WoT overwrites xb/Wt head)
    rope_vtrans_wot_kernel<<<5120, 256, 0, stream>>>(qkv, vtb, Wo, WoT);
    // 4) attention (writes ao; qkv/vtb dead afterwards)
    attn_kernel<<<dim3(16, 16), 512, 0, stream>>>(qkv, vtb, ao);
    // 5) output projection, split-K=3 (1344/1344/1408), partials in dead qkv
    gemm_bt<<<dim3(16, 16, 3), 256, 0, stream>>>(ao, WoT, part, 2048, 4096, 4096, 2048, 1344, 64);
    // 6) reduce partials -> fp32 out
    reduce_kernel<<<2048, 256, 0, stream>>>(part, out);
}